// Round 1
// baseline (634.632 us; speedup 1.0000x reference)
//
#include <hip/hip_runtime.h>
#include <hip/hip_bf16.h>

// GCN stack: N=50000 nodes, E=600000 edges, D=128.
// Pipeline per launch (same work every call; graph-capture safe):
//  1. zero cnt; histogram col -> cnt; dinv = rsqrt(cnt+1)
//  2. single-block segmented scan -> row_ptr/cursor; fill CSR (src, norm) by dest
//  3. layer1: H=x@W1, XR=x@R1, x1=relu(SpMM(H)+XR)   (SpMM in-place on XR)
//     layer2: H=x1@W2, XR=x1@R2 (stored in d_out), x2=relu(SpMM(H)+XR)
//     layer3: H=x2@W3, x3=SpMM(H)
//     head:   out = x3@Wh + bh

__global__ void zero_int_kernel(int* __restrict__ p, int n) {
    int i = blockIdx.x * blockDim.x + threadIdx.x;
    if (i < n) p[i] = 0;
}

__global__ void hist_kernel(const int* __restrict__ col, int* __restrict__ cnt, int E) {
    int i = blockIdx.x * blockDim.x + threadIdx.x;
    if (i < E) atomicAdd(&cnt[col[i]], 1);
}

__global__ void dinv_kernel(const int* __restrict__ cnt, float* __restrict__ dinv, int n) {
    int i = blockIdx.x * blockDim.x + threadIdx.x;
    if (i < n) dinv[i] = rsqrtf((float)(cnt[i] + 1));  // +1 self loop
}

// Single-block exclusive scan of cnt[0..n) -> row_ptr/cursor; row_ptr[n]=E.
__global__ void scan_kernel(const int* __restrict__ cnt, int* __restrict__ row_ptr,
                            int* __restrict__ cursor, int n) {
    const int T = 1024;
    int t = threadIdx.x;
    int seg = (n + T - 1) / T;
    int beg = t * seg;
    int end = beg + seg; if (end > n) end = n;
    int s = 0;
    for (int i = beg; i < end; ++i) s += cnt[i];
    __shared__ int sums[T];
    sums[t] = s;
    __syncthreads();
    for (int off = 1; off < T; off <<= 1) {
        int add = (t >= off) ? sums[t - off] : 0;
        __syncthreads();
        sums[t] += add;
        __syncthreads();
    }
    int prefix = (t == 0) ? 0 : sums[t - 1];
    for (int i = beg; i < end; ++i) {
        row_ptr[i] = prefix;
        cursor[i] = prefix;
        prefix += cnt[i];
    }
    if (t == T - 1) row_ptr[n] = sums[T - 1];
}

__global__ void fill_kernel(const int* __restrict__ row, const int* __restrict__ colv,
                            const float* __restrict__ dinv, int* __restrict__ cursor,
                            int2* __restrict__ csr, int E) {
    int i = blockIdx.x * blockDim.x + threadIdx.x;
    if (i < E) {
        int r = row[i], c = colv[i];
        int p = atomicAdd(&cursor[c], 1);
        float nrm = dinv[r] * dinv[c];
        csr[p] = make_int2(r, __float_as_int(nrm));
    }
}

// out[n,128] = X[n,128] @ W[128,128] (+ bias). fp32 VALU GEMM.
// Block: 256 threads, tile 64 rows x 128 cols, per-thread 4 rows x 8 cols.
// K chunked by 32 through LDS (Xs padded stride 36 -> <=2-way bank conflicts).
__global__ __launch_bounds__(256) void gemm_kernel(
        const float* __restrict__ X, const float* __restrict__ W,
        const float* __restrict__ bias, float* __restrict__ out, int n) {
    __shared__ float Xs[64 * 36];
    __shared__ float Wsc[32 * 128];
    int t = threadIdx.x;
    int r0 = blockIdx.x * 64;
    int ty = t >> 4, tx = t & 15;

    float4 acc[4][2];
#pragma unroll
    for (int i = 0; i < 4; ++i) {
        acc[i][0] = make_float4(0.f, 0.f, 0.f, 0.f);
        acc[i][1] = make_float4(0.f, 0.f, 0.f, 0.f);
    }

    for (int k0 = 0; k0 < 128; k0 += 32) {
        // stage X chunk: 64 rows x 32 k = 512 float4
#pragma unroll
        for (int idx = t; idx < 512; idx += 256) {
            int row = idx >> 3, q = idx & 7;
            int gr = r0 + row;
            float4 v = make_float4(0.f, 0.f, 0.f, 0.f);
            if (gr < n) v = ((const float4*)X)[(size_t)gr * 32 + (k0 >> 2) + q];
            *((float4*)&Xs[row * 36 + q * 4]) = v;
        }
        // stage W chunk: 32 k-rows x 128 cols = 1024 float4
#pragma unroll
        for (int idx = t; idx < 1024; idx += 256) {
            ((float4*)Wsc)[idx] = ((const float4*)W)[(k0 << 5) + idx];
        }
        __syncthreads();

        for (int kl = 0; kl < 32; kl += 4) {
            float4 a[4];
#pragma unroll
            for (int i = 0; i < 4; ++i)
                a[i] = *((const float4*)&Xs[(ty * 4 + i) * 36 + kl]);
#pragma unroll
            for (int kk = 0; kk < 4; ++kk) {
                float4 b0 = *((const float4*)&Wsc[(kl + kk) * 128 + tx * 4]);
                float4 b1 = *((const float4*)&Wsc[(kl + kk) * 128 + 64 + tx * 4]);
#pragma unroll
                for (int i = 0; i < 4; ++i) {
                    float av = (kk == 0) ? a[i].x : (kk == 1) ? a[i].y
                             : (kk == 2) ? a[i].z : a[i].w;
                    acc[i][0].x = fmaf(av, b0.x, acc[i][0].x);
                    acc[i][0].y = fmaf(av, b0.y, acc[i][0].y);
                    acc[i][0].z = fmaf(av, b0.z, acc[i][0].z);
                    acc[i][0].w = fmaf(av, b0.w, acc[i][0].w);
                    acc[i][1].x = fmaf(av, b1.x, acc[i][1].x);
                    acc[i][1].y = fmaf(av, b1.y, acc[i][1].y);
                    acc[i][1].z = fmaf(av, b1.z, acc[i][1].z);
                    acc[i][1].w = fmaf(av, b1.w, acc[i][1].w);
                }
            }
        }
        __syncthreads();
    }

    float4 bb0 = make_float4(0.f, 0.f, 0.f, 0.f), bb1 = bb0;
    if (bias) {
        bb0 = *((const float4*)&bias[tx * 4]);
        bb1 = *((const float4*)&bias[64 + tx * 4]);
    }
#pragma unroll
    for (int i = 0; i < 4; ++i) {
        int gr = r0 + ty * 4 + i;
        if (gr < n) {
            float4 o0 = acc[i][0], o1 = acc[i][1];
            o0.x += bb0.x; o0.y += bb0.y; o0.z += bb0.z; o0.w += bb0.w;
            o1.x += bb1.x; o1.y += bb1.y; o1.z += bb1.z; o1.w += bb1.w;
            ((float4*)out)[(size_t)gr * 32 + tx] = o0;
            ((float4*)out)[(size_t)gr * 32 + 16 + tx] = o1;
        }
    }
}

// One wave per node; lane holds 2 features (float2): 512 B coalesced gather/edge.
// out[i] = sum_e norm_e*h[src_e] + dinv[i]^2*h[i] (+ xr[i]) (relu?)
__global__ void spmm_kernel(const float* __restrict__ h, const float* __restrict__ xr,
                            const int* __restrict__ row_ptr, const int2* __restrict__ csr,
                            const float* __restrict__ dinv, float* __restrict__ out,
                            int n, int do_relu) {
    int gid = blockIdx.x * blockDim.x + threadIdx.x;
    int node = gid >> 6;
    int lane = gid & 63;
    if (node >= n) return;
    const float2* hp = (const float2*)h;
    float di = dinv[node];
    float w = di * di;
    float2 hv = hp[(size_t)node * 64 + lane];
    float2 acc;
    acc.x = hv.x * w;
    acc.y = hv.y * w;
    int e = row_ptr[node], eend = row_ptr[node + 1];
    for (; e < eend; ++e) {
        int2 ed = csr[e];
        float nrm = __int_as_float(ed.y);
        float2 v = hp[(size_t)ed.x * 64 + lane];
        acc.x = fmaf(nrm, v.x, acc.x);
        acc.y = fmaf(nrm, v.y, acc.y);
    }
    if (xr) {
        float2 r = ((const float2*)xr)[(size_t)node * 64 + lane];
        acc.x += r.x;
        acc.y += r.y;
    }
    if (do_relu) {
        acc.x = fmaxf(acc.x, 0.f);
        acc.y = fmaxf(acc.y, 0.f);
    }
    ((float2*)out)[(size_t)node * 64 + lane] = acc;
}

extern "C" void kernel_launch(void* const* d_in, const int* in_sizes, int n_in,
                              void* d_out, int out_size, void* d_ws, size_t ws_size,
                              hipStream_t stream) {
    const float* x  = (const float*)d_in[0];
    const int*   ei = (const int*)d_in[1];
    const float* W1 = (const float*)d_in[2];
    const float* R1 = (const float*)d_in[3];
    const float* W2 = (const float*)d_in[4];
    const float* R2 = (const float*)d_in[5];
    const float* W3 = (const float*)d_in[6];
    const float* Wh = (const float*)d_in[7];
    const float* bh = (const float*)d_in[8];
    float* out = (float*)d_out;

    int N = in_sizes[0] / 128;
    int E = in_sizes[1] / 2;

    char* p = (char*)d_ws;
    auto alloc = [&](size_t bytes) {
        char* r = p;
        p += (bytes + 255) & ~(size_t)255;
        return r;
    };
    int*   cnt     = (int*)alloc((size_t)N * 4);
    int*   row_ptr = (int*)alloc((size_t)(N + 1) * 4);
    int*   cursor  = (int*)alloc((size_t)N * 4);
    float* dinv    = (float*)alloc((size_t)N * 4);
    int2*  csr     = (int2*)alloc((size_t)E * 8);
    float* B0      = (float*)alloc((size_t)N * 128 * 4);
    float* B1      = (float*)alloc((size_t)N * 128 * 4);

    const int* rowi = ei;
    const int* coli = ei + E;

    zero_int_kernel<<<(N + 255) / 256, 256, 0, stream>>>(cnt, N);
    hist_kernel<<<(E + 255) / 256, 256, 0, stream>>>(coli, cnt, E);
    dinv_kernel<<<(N + 255) / 256, 256, 0, stream>>>(cnt, dinv, N);
    scan_kernel<<<1, 1024, 0, stream>>>(cnt, row_ptr, cursor, N);
    fill_kernel<<<(E + 255) / 256, 256, 0, stream>>>(rowi, coli, dinv, cursor, csr, E);

    int gb = (N + 63) / 64;
    int sb = (N + 3) / 4;

    // layer 1: H=B0, XR=B1, x1 -> B1 (in-place residual)
    gemm_kernel<<<gb, 256, 0, stream>>>(x, W1, nullptr, B0, N);
    gemm_kernel<<<gb, 256, 0, stream>>>(x, R1, nullptr, B1, N);
    spmm_kernel<<<sb, 256, 0, stream>>>(B0, B1, row_ptr, csr, dinv, B1, N, 1);
    // layer 2: H=B0, XR=out (scratch), x2 -> out
    gemm_kernel<<<gb, 256, 0, stream>>>(B1, W2, nullptr, B0, N);
    gemm_kernel<<<gb, 256, 0, stream>>>(B1, R2, nullptr, out, N);
    spmm_kernel<<<sb, 256, 0, stream>>>(B0, out, row_ptr, csr, dinv, out, N, 1);
    // layer 3: H=B0, x3 -> B1 (no residual, no relu)
    gemm_kernel<<<gb, 256, 0, stream>>>(out, W3, nullptr, B0, N);
    spmm_kernel<<<sb, 256, 0, stream>>>(B0, nullptr, row_ptr, csr, dinv, B1, N, 0);
    // head: out = B1 @ Wh + bh
    gemm_kernel<<<gb, 256, 0, stream>>>(B1, Wh, bh, out, N);
}

// Round 2
// 542.048 us; speedup vs baseline: 1.1708x; 1.1708x over previous
//
#include <hip/hip_runtime.h>
#include <hip/hip_bf16.h>

// GCN stack: N=50000 nodes, E=600000 edges, D=128.
// Pipeline per launch (same work every call; graph-capture safe):
//  1. zero cnt; histogram col -> cnt; dinv = rsqrt(cnt+1)
//  2. hierarchical scan (reduce/scan-bsums/write) -> row_ptr/cursor;
//     fill CSR (src, norm) by dest
//  3. layer1: H=x@W1, XR=x@R1, x1=relu(SpMM(H)+XR)   (SpMM in-place on XR)
//     layer2: H=x1@W2, XR=x1@R2 (stored in d_out), x2=relu(SpMM(H)+XR)
//     layer3: H=x2@W3, x3=SpMM(H)
//     head:   out = x3@Wh + bh
//
// R1 history: single-block scan_kernel was 111 us (0.14% occupancy, 4.5 GB/s)
// -> replaced with 3-kernel hierarchical scan (chunk=1024).

#define SCAN_CHUNK 1024  // elements per block (256 thr x 4 via int4)

__global__ void zero_int_kernel(int* __restrict__ p, int n) {
    int i = blockIdx.x * blockDim.x + threadIdx.x;
    if (i < n) p[i] = 0;
}

__global__ void hist_kernel(const int* __restrict__ col, int* __restrict__ cnt, int E) {
    int i = blockIdx.x * blockDim.x + threadIdx.x;
    if (i < E) atomicAdd(&cnt[col[i]], 1);
}

__global__ void dinv_kernel(const int* __restrict__ cnt, float* __restrict__ dinv, int n) {
    int i = blockIdx.x * blockDim.x + threadIdx.x;
    if (i < n) dinv[i] = rsqrtf((float)(cnt[i] + 1));  // +1 self loop
}

// ---- hierarchical scan: cnt[0..n) -> exclusive prefix in row_ptr/cursor ----
__global__ __launch_bounds__(256) void scan_reduce_kernel(
        const int* __restrict__ cnt, int* __restrict__ bsum, int n) {
    __shared__ int s[256];
    int b = blockIdx.x, t = threadIdx.x;
    int base = b * SCAN_CHUNK + t * 4;
    int v = 0;
    if (base + 3 < n) {
        int4 q = *(const int4*)&cnt[base];
        v = q.x + q.y + q.z + q.w;
    } else {
        for (int i = 0; i < 4; ++i) if (base + i < n) v += cnt[base + i];
    }
    s[t] = v;
    __syncthreads();
    for (int off = 128; off > 0; off >>= 1) {
        if (t < off) s[t] += s[t + off];
        __syncthreads();
    }
    if (t == 0) bsum[b] = s[0];
}

// single block; nb <= 1024
__global__ __launch_bounds__(1024) void scan_bsum_kernel(
        const int* __restrict__ bsum, int* __restrict__ boff, int nb) {
    __shared__ int s[1024];
    int t = threadIdx.x;
    s[t] = (t < nb) ? bsum[t] : 0;
    __syncthreads();
    for (int off = 1; off < 1024; off <<= 1) {
        int add = (t >= off) ? s[t - off] : 0;
        __syncthreads();
        s[t] += add;
        __syncthreads();
    }
    if (t < nb) boff[t] = (t == 0) ? 0 : s[t - 1];
}

__global__ __launch_bounds__(256) void scan_write_kernel(
        const int* __restrict__ cnt, const int* __restrict__ boff,
        int* __restrict__ row_ptr, int* __restrict__ cursor, int n, int E) {
    __shared__ int s[256];
    int b = blockIdx.x, t = threadIdx.x;
    int base = b * SCAN_CHUNK + t * 4;
    int v[4];
    int sum = 0;
    for (int i = 0; i < 4; ++i) {
        v[i] = (base + i < n) ? cnt[base + i] : 0;
        sum += v[i];
    }
    s[t] = sum;
    __syncthreads();
    for (int off = 1; off < 256; off <<= 1) {
        int add = (t >= off) ? s[t - off] : 0;
        __syncthreads();
        s[t] += add;
        __syncthreads();
    }
    int prefix = boff[b] + ((t == 0) ? 0 : s[t - 1]);
    for (int i = 0; i < 4; ++i) {
        if (base + i < n) {
            row_ptr[base + i] = prefix;
            cursor[base + i] = prefix;
            prefix += v[i];
        }
    }
    if (b == 0 && t == 0) row_ptr[n] = E;
}

__global__ void fill_kernel(const int* __restrict__ row, const int* __restrict__ colv,
                            const float* __restrict__ dinv, int* __restrict__ cursor,
                            int2* __restrict__ csr, int E) {
    int i = blockIdx.x * blockDim.x + threadIdx.x;
    if (i < E) {
        int r = row[i], c = colv[i];
        int p = atomicAdd(&cursor[c], 1);
        float nrm = dinv[r] * dinv[c];
        csr[p] = make_int2(r, __float_as_int(nrm));
    }
}

// out[n,128] = X[n,128] @ W[128,128] (+ bias). fp32 VALU GEMM.
// Block: 256 threads, tile 64 rows x 128 cols, per-thread 4 rows x 8 cols.
// K chunked by 32 through LDS (Xs padded stride 36 -> <=2-way bank conflicts).
__global__ __launch_bounds__(256) void gemm_kernel(
        const float* __restrict__ X, const float* __restrict__ W,
        const float* __restrict__ bias, float* __restrict__ out, int n) {
    __shared__ float Xs[64 * 36];
    __shared__ float Wsc[32 * 128];
    int t = threadIdx.x;
    int r0 = blockIdx.x * 64;
    int ty = t >> 4, tx = t & 15;

    float4 acc[4][2];
#pragma unroll
    for (int i = 0; i < 4; ++i) {
        acc[i][0] = make_float4(0.f, 0.f, 0.f, 0.f);
        acc[i][1] = make_float4(0.f, 0.f, 0.f, 0.f);
    }

    for (int k0 = 0; k0 < 128; k0 += 32) {
        // stage X chunk: 64 rows x 32 k = 512 float4
#pragma unroll
        for (int idx = t; idx < 512; idx += 256) {
            int row = idx >> 3, q = idx & 7;
            int gr = r0 + row;
            float4 v = make_float4(0.f, 0.f, 0.f, 0.f);
            if (gr < n) v = ((const float4*)X)[(size_t)gr * 32 + (k0 >> 2) + q];
            *((float4*)&Xs[row * 36 + q * 4]) = v;
        }
        // stage W chunk: 32 k-rows x 128 cols = 1024 float4
#pragma unroll
        for (int idx = t; idx < 1024; idx += 256) {
            ((float4*)Wsc)[idx] = ((const float4*)W)[(k0 << 5) + idx];
        }
        __syncthreads();

        for (int kl = 0; kl < 32; kl += 4) {
            float4 a[4];
#pragma unroll
            for (int i = 0; i < 4; ++i)
                a[i] = *((const float4*)&Xs[(ty * 4 + i) * 36 + kl]);
#pragma unroll
            for (int kk = 0; kk < 4; ++kk) {
                float4 b0 = *((const float4*)&Wsc[(kl + kk) * 128 + tx * 4]);
                float4 b1 = *((const float4*)&Wsc[(kl + kk) * 128 + 64 + tx * 4]);
#pragma unroll
                for (int i = 0; i < 4; ++i) {
                    float av = (kk == 0) ? a[i].x : (kk == 1) ? a[i].y
                             : (kk == 2) ? a[i].z : a[i].w;
                    acc[i][0].x = fmaf(av, b0.x, acc[i][0].x);
                    acc[i][0].y = fmaf(av, b0.y, acc[i][0].y);
                    acc[i][0].z = fmaf(av, b0.z, acc[i][0].z);
                    acc[i][0].w = fmaf(av, b0.w, acc[i][0].w);
                    acc[i][1].x = fmaf(av, b1.x, acc[i][1].x);
                    acc[i][1].y = fmaf(av, b1.y, acc[i][1].y);
                    acc[i][1].z = fmaf(av, b1.z, acc[i][1].z);
                    acc[i][1].w = fmaf(av, b1.w, acc[i][1].w);
                }
            }
        }
        __syncthreads();
    }

    float4 bb0 = make_float4(0.f, 0.f, 0.f, 0.f), bb1 = bb0;
    if (bias) {
        bb0 = *((const float4*)&bias[tx * 4]);
        bb1 = *((const float4*)&bias[64 + tx * 4]);
    }
#pragma unroll
    for (int i = 0; i < 4; ++i) {
        int gr = r0 + ty * 4 + i;
        if (gr < n) {
            float4 o0 = acc[i][0], o1 = acc[i][1];
            o0.x += bb0.x; o0.y += bb0.y; o0.z += bb0.z; o0.w += bb0.w;
            o1.x += bb1.x; o1.y += bb1.y; o1.z += bb1.z; o1.w += bb1.w;
            ((float4*)out)[(size_t)gr * 32 + tx] = o0;
            ((float4*)out)[(size_t)gr * 32 + 16 + tx] = o1;
        }
    }
}

// One wave per node; lane holds 2 features (float2): 512 B coalesced gather/edge.
// out[i] = sum_e norm_e*h[src_e] + dinv[i]^2*h[i] (+ xr[i]) (relu?)
__global__ void spmm_kernel(const float* __restrict__ h, const float* __restrict__ xr,
                            const int* __restrict__ row_ptr, const int2* __restrict__ csr,
                            const float* __restrict__ dinv, float* __restrict__ out,
                            int n, int do_relu) {
    int gid = blockIdx.x * blockDim.x + threadIdx.x;
    int node = gid >> 6;
    int lane = gid & 63;
    if (node >= n) return;
    const float2* hp = (const float2*)h;
    float di = dinv[node];
    float w = di * di;
    float2 hv = hp[(size_t)node * 64 + lane];
    float2 acc;
    acc.x = hv.x * w;
    acc.y = hv.y * w;
    int e = row_ptr[node], eend = row_ptr[node + 1];
    for (; e < eend; ++e) {
        int2 ed = csr[e];
        float nrm = __int_as_float(ed.y);
        float2 v = hp[(size_t)ed.x * 64 + lane];
        acc.x = fmaf(nrm, v.x, acc.x);
        acc.y = fmaf(nrm, v.y, acc.y);
    }
    if (xr) {
        float2 r = ((const float2*)xr)[(size_t)node * 64 + lane];
        acc.x += r.x;
        acc.y += r.y;
    }
    if (do_relu) {
        acc.x = fmaxf(acc.x, 0.f);
        acc.y = fmaxf(acc.y, 0.f);
    }
    ((float2*)out)[(size_t)node * 64 + lane] = acc;
}

extern "C" void kernel_launch(void* const* d_in, const int* in_sizes, int n_in,
                              void* d_out, int out_size, void* d_ws, size_t ws_size,
                              hipStream_t stream) {
    const float* x  = (const float*)d_in[0];
    const int*   ei = (const int*)d_in[1];
    const float* W1 = (const float*)d_in[2];
    const float* R1 = (const float*)d_in[3];
    const float* W2 = (const float*)d_in[4];
    const float* R2 = (const float*)d_in[5];
    const float* W3 = (const float*)d_in[6];
    const float* Wh = (const float*)d_in[7];
    const float* bh = (const float*)d_in[8];
    float* out = (float*)d_out;

    int N = in_sizes[0] / 128;
    int E = in_sizes[1] / 2;

    char* p = (char*)d_ws;
    auto alloc = [&](size_t bytes) {
        char* r = p;
        p += (bytes + 255) & ~(size_t)255;
        return r;
    };
    int*   cnt     = (int*)alloc((size_t)N * 4);
    int*   row_ptr = (int*)alloc((size_t)(N + 1) * 4);
    int*   cursor  = (int*)alloc((size_t)N * 4);
    float* dinv    = (float*)alloc((size_t)N * 4);
    int*   bsum    = (int*)alloc((size_t)1024 * 4);
    int*   boff    = (int*)alloc((size_t)1024 * 4);
    int2*  csr     = (int2*)alloc((size_t)E * 8);
    float* B0      = (float*)alloc((size_t)N * 128 * 4);
    float* B1      = (float*)alloc((size_t)N * 128 * 4);

    const int* rowi = ei;
    const int* coli = ei + E;

    int nb = (N + SCAN_CHUNK - 1) / SCAN_CHUNK;

    zero_int_kernel<<<(N + 255) / 256, 256, 0, stream>>>(cnt, N);
    hist_kernel<<<(E + 255) / 256, 256, 0, stream>>>(coli, cnt, E);
    dinv_kernel<<<(N + 255) / 256, 256, 0, stream>>>(cnt, dinv, N);
    scan_reduce_kernel<<<nb, 256, 0, stream>>>(cnt, bsum, N);
    scan_bsum_kernel<<<1, 1024, 0, stream>>>(bsum, boff, nb);
    scan_write_kernel<<<nb, 256, 0, stream>>>(cnt, boff, row_ptr, cursor, N, E);
    fill_kernel<<<(E + 255) / 256, 256, 0, stream>>>(rowi, coli, dinv, cursor, csr, E);

    int gb = (N + 63) / 64;
    int sb = (N + 3) / 4;

    // layer 1: H=B0, XR=B1, x1 -> B1 (in-place residual)
    gemm_kernel<<<gb, 256, 0, stream>>>(x, W1, nullptr, B0, N);
    gemm_kernel<<<gb, 256, 0, stream>>>(x, R1, nullptr, B1, N);
    spmm_kernel<<<sb, 256, 0, stream>>>(B0, B1, row_ptr, csr, dinv, B1, N, 1);
    // layer 2: H=B0, XR=out (scratch), x2 -> out
    gemm_kernel<<<gb, 256, 0, stream>>>(B1, W2, nullptr, B0, N);
    gemm_kernel<<<gb, 256, 0, stream>>>(B1, R2, nullptr, out, N);
    spmm_kernel<<<sb, 256, 0, stream>>>(B0, out, row_ptr, csr, dinv, out, N, 1);
    // layer 3: H=B0, x3 -> B1 (no residual, no relu)
    gemm_kernel<<<gb, 256, 0, stream>>>(out, W3, nullptr, B0, N);
    spmm_kernel<<<sb, 256, 0, stream>>>(B0, nullptr, row_ptr, csr, dinv, B1, N, 0);
    // head: out = B1 @ Wh + bh
    gemm_kernel<<<gb, 256, 0, stream>>>(B1, Wh, bh, out, N);
}

// Round 3
// 422.137 us; speedup vs baseline: 1.5034x; 1.2841x over previous
//
#include <hip/hip_runtime.h>
#include <hip/hip_bf16.h>

// GCN stack: N=50000 nodes, E=600000 edges, D=128.
//  1. zero cnt; histogram col -> cnt; dinv = rsqrt(cnt+1)
//  2. hierarchical scan -> row_ptr/cursor; fill CSR (src,norm) by dest
//  3. wcvt: all 6 weight matrices fp32 [k][c] -> f16 transposed [c][k]
//  4. layers via f16-MFMA GEMM (fp32 accum) + fp32 SpMM (4-wide unrolled)
//
// R1: single-block scan 111us -> hierarchical (total 634->542)
// R2: fp32 VALU GEMM (~47us each) -> f16 MFMA (16x16x32, fp32 acc);
//     SpMM gather chain unrolled x4 (was 1 outstanding gather/wave).

#define SCAN_CHUNK 1024

typedef _Float16 half8 __attribute__((ext_vector_type(8)));
typedef _Float16 half4 __attribute__((ext_vector_type(4)));
typedef float floatx4 __attribute__((ext_vector_type(4)));

__global__ void zero_int_kernel(int* __restrict__ p, int n) {
    int i = blockIdx.x * blockDim.x + threadIdx.x;
    if (i < n) p[i] = 0;
}

__global__ void hist_kernel(const int* __restrict__ col, int* __restrict__ cnt, int E) {
    int i = blockIdx.x * blockDim.x + threadIdx.x;
    if (i < E) atomicAdd(&cnt[col[i]], 1);
}

__global__ void dinv_kernel(const int* __restrict__ cnt, float* __restrict__ dinv, int n) {
    int i = blockIdx.x * blockDim.x + threadIdx.x;
    if (i < n) dinv[i] = rsqrtf((float)(cnt[i] + 1));
}

__global__ __launch_bounds__(256) void scan_reduce_kernel(
        const int* __restrict__ cnt, int* __restrict__ bsum, int n) {
    __shared__ int s[256];
    int b = blockIdx.x, t = threadIdx.x;
    int base = b * SCAN_CHUNK + t * 4;
    int v = 0;
    if (base + 3 < n) {
        int4 q = *(const int4*)&cnt[base];
        v = q.x + q.y + q.z + q.w;
    } else {
        for (int i = 0; i < 4; ++i) if (base + i < n) v += cnt[base + i];
    }
    s[t] = v;
    __syncthreads();
    for (int off = 128; off > 0; off >>= 1) {
        if (t < off) s[t] += s[t + off];
        __syncthreads();
    }
    if (t == 0) bsum[b] = s[0];
}

__global__ __launch_bounds__(1024) void scan_bsum_kernel(
        const int* __restrict__ bsum, int* __restrict__ boff, int nb) {
    __shared__ int s[1024];
    int t = threadIdx.x;
    s[t] = (t < nb) ? bsum[t] : 0;
    __syncthreads();
    for (int off = 1; off < 1024; off <<= 1) {
        int add = (t >= off) ? s[t - off] : 0;
        __syncthreads();
        s[t] += add;
        __syncthreads();
    }
    if (t < nb) boff[t] = (t == 0) ? 0 : s[t - 1];
}

__global__ __launch_bounds__(256) void scan_write_kernel(
        const int* __restrict__ cnt, const int* __restrict__ boff,
        int* __restrict__ row_ptr, int* __restrict__ cursor, int n, int E) {
    __shared__ int s[256];
    int b = blockIdx.x, t = threadIdx.x;
    int base = b * SCAN_CHUNK + t * 4;
    int v[4];
    int sum = 0;
    for (int i = 0; i < 4; ++i) {
        v[i] = (base + i < n) ? cnt[base + i] : 0;
        sum += v[i];
    }
    s[t] = sum;
    __syncthreads();
    for (int off = 1; off < 256; off <<= 1) {
        int add = (t >= off) ? s[t - off] : 0;
        __syncthreads();
        s[t] += add;
        __syncthreads();
    }
    int prefix = boff[b] + ((t == 0) ? 0 : s[t - 1]);
    for (int i = 0; i < 4; ++i) {
        if (base + i < n) {
            row_ptr[base + i] = prefix;
            cursor[base + i] = prefix;
            prefix += v[i];
        }
    }
    if (b == 0 && t == 0) row_ptr[n] = E;
}

__global__ void fill_kernel(const int* __restrict__ row, const int* __restrict__ colv,
                            const float* __restrict__ dinv, int* __restrict__ cursor,
                            int2* __restrict__ csr, int E) {
    int i = blockIdx.x * blockDim.x + threadIdx.x;
    if (i < E) {
        int r = row[i], c = colv[i];
        int p = atomicAdd(&cursor[c], 1);
        float nrm = dinv[r] * dinv[c];
        csr[p] = make_int2(r, __float_as_int(nrm));
    }
}

// All 6 weights: fp32 W[k][c] -> f16 Wt[c][k] (row-major [128][128]).
// Grid 96 blocks: block b -> matrix b>>4, 32x32 tile b&15.
__global__ __launch_bounds__(256) void wcvt_kernel(
        const float* __restrict__ W1, const float* __restrict__ R1,
        const float* __restrict__ W2, const float* __restrict__ R2,
        const float* __restrict__ W3, const float* __restrict__ Wh,
        _Float16* __restrict__ Wt) {
    __shared__ float tile[32][33];
    int b = blockIdx.x;
    int mat = b >> 4, tl = b & 15;
    const float* W = (mat == 0) ? W1 : (mat == 1) ? R1 : (mat == 2) ? W2
                   : (mat == 3) ? R2 : (mat == 4) ? W3 : Wh;
    _Float16* T = Wt + (size_t)mat * 16384;
    int tr = (tl >> 2) * 32, tc = (tl & 3) * 32;
    int t = threadIdx.x;
    int i = t >> 3, j4 = t & 7;
    float4 v = *(const float4*)&W[(tr + i) * 128 + tc + j4 * 4];
    tile[i][j4 * 4 + 0] = v.x;
    tile[i][j4 * 4 + 1] = v.y;
    tile[i][j4 * 4 + 2] = v.z;
    tile[i][j4 * 4 + 3] = v.w;
    __syncthreads();
    half4 h;
    h.x = (_Float16)tile[j4 * 4 + 0][i];
    h.y = (_Float16)tile[j4 * 4 + 1][i];
    h.z = (_Float16)tile[j4 * 4 + 2][i];
    h.w = (_Float16)tile[j4 * 4 + 3][i];
    *(half4*)&T[(tc + i) * 128 + tr + j4 * 4] = h;
}

// out[n,128] = X[n,128] @ W[128,128] (+bias) via v_mfma_f32_16x16x32_f16.
// Block: 256 thr = 4 waves, 64 rows x 128 cols; wave w owns rows w*16..+15.
// LDS row stride 136 f16 (272 B) -> frag reads ~2-way conflicts (free).
// Fragment layouts (HW-verified, guide §3): A[m=lane&15][k=quad*8+j],
// B[k=quad*8+j][n=lane&15], C/D col=lane&15 row=quad*4+reg.
__global__ __launch_bounds__(256) void gemm_f16_kernel(
        const float* __restrict__ X, const _Float16* __restrict__ Wt,
        const float* __restrict__ bias, float* __restrict__ out, int n) {
    __shared__ _Float16 Af[64 * 136];
    __shared__ _Float16 Bt[128 * 136];
    int t = threadIdx.x;
    int r0 = blockIdx.x * 64;

    // stage A: 64 rows x 128 k fp32 -> f16 (zero-pad OOB rows)
#pragma unroll
    for (int i = 0; i < 8; ++i) {
        int flat = i * 256 + t;
        int r = flat >> 5, c4 = flat & 31;
        float4 v = make_float4(0.f, 0.f, 0.f, 0.f);
        if (r0 + r < n) v = *(const float4*)&X[(size_t)(r0 + r) * 128 + c4 * 4];
        half4 h;
        h.x = (_Float16)v.x; h.y = (_Float16)v.y;
        h.z = (_Float16)v.z; h.w = (_Float16)v.w;
        *(half4*)&Af[r * 136 + c4 * 4] = h;
    }
    // stage Bt: 128 rows (cols of W) x 128 k, f16 verbatim
#pragma unroll
    for (int i = 0; i < 8; ++i) {
        int flat = i * 256 + t;
        int c = flat >> 4, k8 = flat & 15;
        half8 w = *(const half8*)&Wt[c * 128 + k8 * 8];
        *(half8*)&Bt[c * 136 + k8 * 8] = w;
    }
    __syncthreads();

    int lane = t & 63, w = t >> 6;
    int m = lane & 15, q = lane >> 4;

    floatx4 acc[8];
#pragma unroll
    for (int nt = 0; nt < 8; ++nt) acc[nt] = (floatx4){0.f, 0.f, 0.f, 0.f};

#pragma unroll
    for (int s = 0; s < 4; ++s) {
        half8 a = *(const half8*)&Af[(w * 16 + m) * 136 + s * 32 + q * 8];
#pragma unroll
        for (int nt = 0; nt < 8; ++nt) {
            half8 b = *(const half8*)&Bt[(nt * 16 + m) * 136 + s * 32 + q * 8];
            acc[nt] = __builtin_amdgcn_mfma_f32_16x16x32_f16(a, b, acc[nt], 0, 0, 0);
        }
    }

    int rowb = r0 + w * 16 + q * 4;
#pragma unroll
    for (int nt = 0; nt < 8; ++nt) {
        int col = nt * 16 + m;
        float bb = bias ? bias[col] : 0.f;
#pragma unroll
        for (int r = 0; r < 4; ++r) {
            int gr = rowb + r;
            if (gr < n) out[(size_t)gr * 128 + col] = acc[nt][r] + bb;
        }
    }
}

// One wave per node; lane = 2 features (float2). Edge loop unrolled x4:
// 4 independent csr loads then 4 independent gathers in flight per wave.
__global__ void spmm_kernel(const float* __restrict__ h, const float* __restrict__ xr,
                            const int* __restrict__ row_ptr, const int2* __restrict__ csr,
                            const float* __restrict__ dinv, float* __restrict__ out,
                            int n, int do_relu) {
    int gid = blockIdx.x * blockDim.x + threadIdx.x;
    int node = gid >> 6;
    int lane = gid & 63;
    if (node >= n) return;
    const float2* hp = (const float2*)h;
    float di = dinv[node];
    float w = di * di;
    float2 hv = hp[(size_t)node * 64 + lane];
    float accx = hv.x * w, accy = hv.y * w;
    int e = row_ptr[node], eend = row_ptr[node + 1];
    for (; e + 4 <= eend; e += 4) {
        int2 d0 = csr[e], d1 = csr[e + 1], d2 = csr[e + 2], d3 = csr[e + 3];
        float2 v0 = hp[(size_t)d0.x * 64 + lane];
        float2 v1 = hp[(size_t)d1.x * 64 + lane];
        float2 v2 = hp[(size_t)d2.x * 64 + lane];
        float2 v3 = hp[(size_t)d3.x * 64 + lane];
        float n0 = __int_as_float(d0.y), n1 = __int_as_float(d1.y);
        float n2 = __int_as_float(d2.y), n3 = __int_as_float(d3.y);
        accx = fmaf(n0, v0.x, accx); accy = fmaf(n0, v0.y, accy);
        accx = fmaf(n1, v1.x, accx); accy = fmaf(n1, v1.y, accy);
        accx = fmaf(n2, v2.x, accx); accy = fmaf(n2, v2.y, accy);
        accx = fmaf(n3, v3.x, accx); accy = fmaf(n3, v3.y, accy);
    }
    for (; e < eend; ++e) {
        int2 ed = csr[e];
        float nrm = __int_as_float(ed.y);
        float2 v = hp[(size_t)ed.x * 64 + lane];
        accx = fmaf(nrm, v.x, accx);
        accy = fmaf(nrm, v.y, accy);
    }
    if (xr) {
        float2 r = ((const float2*)xr)[(size_t)node * 64 + lane];
        accx += r.x;
        accy += r.y;
    }
    if (do_relu) {
        accx = fmaxf(accx, 0.f);
        accy = fmaxf(accy, 0.f);
    }
    float2 o; o.x = accx; o.y = accy;
    ((float2*)out)[(size_t)node * 64 + lane] = o;
}

extern "C" void kernel_launch(void* const* d_in, const int* in_sizes, int n_in,
                              void* d_out, int out_size, void* d_ws, size_t ws_size,
                              hipStream_t stream) {
    const float* x  = (const float*)d_in[0];
    const int*   ei = (const int*)d_in[1];
    const float* W1 = (const float*)d_in[2];
    const float* R1 = (const float*)d_in[3];
    const float* W2 = (const float*)d_in[4];
    const float* R2 = (const float*)d_in[5];
    const float* W3 = (const float*)d_in[6];
    const float* Wh = (const float*)d_in[7];
    const float* bh = (const float*)d_in[8];
    float* out = (float*)d_out;

    int N = in_sizes[0] / 128;
    int E = in_sizes[1] / 2;

    char* p = (char*)d_ws;
    auto alloc = [&](size_t bytes) {
        char* r = p;
        p += (bytes + 255) & ~(size_t)255;
        return r;
    };
    int*      cnt     = (int*)alloc((size_t)N * 4);
    int*      row_ptr = (int*)alloc((size_t)(N + 1) * 4);
    int*      cursor  = (int*)alloc((size_t)N * 4);
    float*    dinv    = (float*)alloc((size_t)N * 4);
    int*      bsum    = (int*)alloc((size_t)1024 * 4);
    int*      boff    = (int*)alloc((size_t)1024 * 4);
    int2*     csr     = (int2*)alloc((size_t)E * 8);
    _Float16* Wt      = (_Float16*)alloc((size_t)6 * 16384 * 2);
    float*    B0      = (float*)alloc((size_t)N * 128 * 4);
    float*    B1      = (float*)alloc((size_t)N * 128 * 4);

    const int* rowi = ei;
    const int* coli = ei + E;

    int nb = (N + SCAN_CHUNK - 1) / SCAN_CHUNK;

    zero_int_kernel<<<(N + 255) / 256, 256, 0, stream>>>(cnt, N);
    hist_kernel<<<(E + 255) / 256, 256, 0, stream>>>(coli, cnt, E);
    dinv_kernel<<<(N + 255) / 256, 256, 0, stream>>>(cnt, dinv, N);
    scan_reduce_kernel<<<nb, 256, 0, stream>>>(cnt, bsum, N);
    scan_bsum_kernel<<<1, 1024, 0, stream>>>(bsum, boff, nb);
    scan_write_kernel<<<nb, 256, 0, stream>>>(cnt, boff, row_ptr, cursor, N, E);
    fill_kernel<<<(E + 255) / 256, 256, 0, stream>>>(rowi, coli, dinv, cursor, csr, E);
    wcvt_kernel<<<96, 256, 0, stream>>>(W1, R1, W2, R2, W3, Wh, Wt);

    int gb = (N + 63) / 64;
    int sb = (N + 3) / 4;
    _Float16* Wt1 = Wt;
    _Float16* Rt1 = Wt + 16384;
    _Float16* Wt2 = Wt + 2 * 16384;
    _Float16* Rt2 = Wt + 3 * 16384;
    _Float16* Wt3 = Wt + 4 * 16384;
    _Float16* Wth = Wt + 5 * 16384;

    // layer 1: H=B0, XR=B1, x1 -> B1
    gemm_f16_kernel<<<gb, 256, 0, stream>>>(x, Wt1, nullptr, B0, N);
    gemm_f16_kernel<<<gb, 256, 0, stream>>>(x, Rt1, nullptr, B1, N);
    spmm_kernel<<<sb, 256, 0, stream>>>(B0, B1, row_ptr, csr, dinv, B1, N, 1);
    // layer 2: H=B0, XR=out (scratch), x2 -> out
    gemm_f16_kernel<<<gb, 256, 0, stream>>>(B1, Wt2, nullptr, B0, N);
    gemm_f16_kernel<<<gb, 256, 0, stream>>>(B1, Rt2, nullptr, out, N);
    spmm_kernel<<<sb, 256, 0, stream>>>(B0, out, row_ptr, csr, dinv, out, N, 1);
    // layer 3: H=B0, x3 -> B1
    gemm_f16_kernel<<<gb, 256, 0, stream>>>(out, Wt3, nullptr, B0, N);
    spmm_kernel<<<sb, 256, 0, stream>>>(B0, nullptr, row_ptr, csr, dinv, B1, N, 0);
    // head
    gemm_f16_kernel<<<gb, 256, 0, stream>>>(B1, Wth, bh, out, N);
}

// Round 4
// 339.968 us; speedup vs baseline: 1.8667x; 1.2417x over previous
//
#include <hip/hip_runtime.h>
#include <hip/hip_bf16.h>

// GCN stack: N=50000 nodes, E=600000 edges, D=128.
//  1. zero cnt; histogram col -> cnt; dinv = rsqrt(cnt+1)
//  2. hierarchical scan -> row_ptr/cursor; fill CSR (src,norm) by dest
//  3. wcvt: weights fp32 [k][c] -> f16 transposed [c][k]; cvt: x fp32 -> f16
//  4. layers via f16-MFMA GEMM (f16 I/O, fp32 accum) + SpMM (f16 gather,
//     fp32 accum, 4-wide unrolled); head GEMM writes fp32 + bias.
//
// R1: single-block scan 111us -> hierarchical (634->542)
// R2: fp32 VALU GEMM -> f16 MFMA; SpMM unroll x4 (542->422)
// R3: all activations f16 (gather row 512B->256B; FETCH 157MB -> ~85MB/SpMM)

#define SCAN_CHUNK 1024

typedef _Float16 half8 __attribute__((ext_vector_type(8)));
typedef _Float16 half4 __attribute__((ext_vector_type(4)));
typedef _Float16 half2v __attribute__((ext_vector_type(2)));
typedef float floatx4 __attribute__((ext_vector_type(4)));

__global__ void zero_int_kernel(int* __restrict__ p, int n) {
    int i = blockIdx.x * blockDim.x + threadIdx.x;
    if (i < n) p[i] = 0;
}

__global__ void hist_kernel(const int* __restrict__ col, int* __restrict__ cnt, int E) {
    int i = blockIdx.x * blockDim.x + threadIdx.x;
    if (i < E) atomicAdd(&cnt[col[i]], 1);
}

__global__ void dinv_kernel(const int* __restrict__ cnt, float* __restrict__ dinv, int n) {
    int i = blockIdx.x * blockDim.x + threadIdx.x;
    if (i < n) dinv[i] = rsqrtf((float)(cnt[i] + 1));
}

__global__ __launch_bounds__(256) void scan_reduce_kernel(
        const int* __restrict__ cnt, int* __restrict__ bsum, int n) {
    __shared__ int s[256];
    int b = blockIdx.x, t = threadIdx.x;
    int base = b * SCAN_CHUNK + t * 4;
    int v = 0;
    if (base + 3 < n) {
        int4 q = *(const int4*)&cnt[base];
        v = q.x + q.y + q.z + q.w;
    } else {
        for (int i = 0; i < 4; ++i) if (base + i < n) v += cnt[base + i];
    }
    s[t] = v;
    __syncthreads();
    for (int off = 128; off > 0; off >>= 1) {
        if (t < off) s[t] += s[t + off];
        __syncthreads();
    }
    if (t == 0) bsum[b] = s[0];
}

__global__ __launch_bounds__(1024) void scan_bsum_kernel(
        const int* __restrict__ bsum, int* __restrict__ boff, int nb) {
    __shared__ int s[1024];
    int t = threadIdx.x;
    s[t] = (t < nb) ? bsum[t] : 0;
    __syncthreads();
    for (int off = 1; off < 1024; off <<= 1) {
        int add = (t >= off) ? s[t - off] : 0;
        __syncthreads();
        s[t] += add;
        __syncthreads();
    }
    if (t < nb) boff[t] = (t == 0) ? 0 : s[t - 1];
}

__global__ __launch_bounds__(256) void scan_write_kernel(
        const int* __restrict__ cnt, const int* __restrict__ boff,
        int* __restrict__ row_ptr, int* __restrict__ cursor, int n, int E) {
    __shared__ int s[256];
    int b = blockIdx.x, t = threadIdx.x;
    int base = b * SCAN_CHUNK + t * 4;
    int v[4];
    int sum = 0;
    for (int i = 0; i < 4; ++i) {
        v[i] = (base + i < n) ? cnt[base + i] : 0;
        sum += v[i];
    }
    s[t] = sum;
    __syncthreads();
    for (int off = 1; off < 256; off <<= 1) {
        int add = (t >= off) ? s[t - off] : 0;
        __syncthreads();
        s[t] += add;
        __syncthreads();
    }
    int prefix = boff[b] + ((t == 0) ? 0 : s[t - 1]);
    for (int i = 0; i < 4; ++i) {
        if (base + i < n) {
            row_ptr[base + i] = prefix;
            cursor[base + i] = prefix;
            prefix += v[i];
        }
    }
    if (b == 0 && t == 0) row_ptr[n] = E;
}

__global__ void fill_kernel(const int* __restrict__ row, const int* __restrict__ colv,
                            const float* __restrict__ dinv, int* __restrict__ cursor,
                            int2* __restrict__ csr, int E) {
    int i = blockIdx.x * blockDim.x + threadIdx.x;
    if (i < E) {
        int r = row[i], c = colv[i];
        int p = atomicAdd(&cursor[c], 1);
        float nrm = dinv[r] * dinv[c];
        csr[p] = make_int2(r, __float_as_int(nrm));
    }
}

// All 6 weights: fp32 W[k][c] -> f16 Wt[c][k] (row-major [128][128]).
__global__ __launch_bounds__(256) void wcvt_kernel(
        const float* __restrict__ W1, const float* __restrict__ R1,
        const float* __restrict__ W2, const float* __restrict__ R2,
        const float* __restrict__ W3, const float* __restrict__ Wh,
        _Float16* __restrict__ Wt) {
    __shared__ float tile[32][33];
    int b = blockIdx.x;
    int mat = b >> 4, tl = b & 15;
    const float* W = (mat == 0) ? W1 : (mat == 1) ? R1 : (mat == 2) ? W2
                   : (mat == 3) ? R2 : (mat == 4) ? W3 : Wh;
    _Float16* T = Wt + (size_t)mat * 16384;
    int tr = (tl >> 2) * 32, tc = (tl & 3) * 32;
    int t = threadIdx.x;
    int i = t >> 3, j4 = t & 7;
    float4 v = *(const float4*)&W[(tr + i) * 128 + tc + j4 * 4];
    tile[i][j4 * 4 + 0] = v.x;
    tile[i][j4 * 4 + 1] = v.y;
    tile[i][j4 * 4 + 2] = v.z;
    tile[i][j4 * 4 + 3] = v.w;
    __syncthreads();
    half4 h;
    h.x = (_Float16)tile[j4 * 4 + 0][i];
    h.y = (_Float16)tile[j4 * 4 + 1][i];
    h.z = (_Float16)tile[j4 * 4 + 2][i];
    h.w = (_Float16)tile[j4 * 4 + 3][i];
    *(half4*)&T[(tc + i) * 128 + tr + j4 * 4] = h;
}

// fp32 -> f16 elementwise (n elements, n % 4 == 0 here)
__global__ void cvt_kernel(const float* __restrict__ x, _Float16* __restrict__ xh, int n) {
    int i = (blockIdx.x * blockDim.x + threadIdx.x) * 4;
    if (i + 3 < n) {
        float4 v = *(const float4*)&x[i];
        half4 h;
        h.x = (_Float16)v.x; h.y = (_Float16)v.y;
        h.z = (_Float16)v.z; h.w = (_Float16)v.w;
        *(half4*)&xh[i] = h;
    } else {
        for (int j = i; j < n; ++j) xh[j] = (_Float16)x[j];
    }
}

// out[n,128] = X[n,128] @ W[128,128], f16 in / f16 out, fp32 accum.
// Block: 256 thr = 4 waves, 64 rows x 128 cols; wave w owns rows w*16..+15.
// Fragment layouts (HW-verified, guide §3): A[m=lane&15][k=quad*8+j],
// B[k=quad*8+j][n=lane&15], C/D col=lane&15 row=quad*4+reg.
__global__ __launch_bounds__(256) void gemm_h_kernel(
        const _Float16* __restrict__ X, const _Float16* __restrict__ Wt,
        _Float16* __restrict__ out, int n) {
    __shared__ _Float16 Af[64 * 136];
    __shared__ _Float16 Bt[128 * 136];
    int t = threadIdx.x;
    int r0 = blockIdx.x * 64;

#pragma unroll
    for (int i = 0; i < 4; ++i) {
        int flat = i * 256 + t;
        int r = flat >> 4, k8 = flat & 15;
        half8 v = {0, 0, 0, 0, 0, 0, 0, 0};
        if (r0 + r < n) v = *(const half8*)&X[(size_t)(r0 + r) * 128 + k8 * 8];
        *(half8*)&Af[r * 136 + k8 * 8] = v;
    }
#pragma unroll
    for (int i = 0; i < 8; ++i) {
        int flat = i * 256 + t;
        int c = flat >> 4, k8 = flat & 15;
        *(half8*)&Bt[c * 136 + k8 * 8] = *(const half8*)&Wt[c * 128 + k8 * 8];
    }
    __syncthreads();

    int lane = t & 63, w = t >> 6;
    int m = lane & 15, q = lane >> 4;

    floatx4 acc[8];
#pragma unroll
    for (int nt = 0; nt < 8; ++nt) acc[nt] = (floatx4){0.f, 0.f, 0.f, 0.f};

#pragma unroll
    for (int s = 0; s < 4; ++s) {
        half8 a = *(const half8*)&Af[(w * 16 + m) * 136 + s * 32 + q * 8];
#pragma unroll
        for (int nt = 0; nt < 8; ++nt) {
            half8 b = *(const half8*)&Bt[(nt * 16 + m) * 136 + s * 32 + q * 8];
            acc[nt] = __builtin_amdgcn_mfma_f32_16x16x32_f16(a, b, acc[nt], 0, 0, 0);
        }
    }

    int rowb = r0 + w * 16 + q * 4;
#pragma unroll
    for (int nt = 0; nt < 8; ++nt) {
        int col = nt * 16 + m;
#pragma unroll
        for (int r = 0; r < 4; ++r) {
            int gr = rowb + r;
            if (gr < n) out[(size_t)gr * 128 + col] = (_Float16)acc[nt][r];
        }
    }
}

// Head: f16 in, fp32 out + bias.
__global__ __launch_bounds__(256) void gemm_f_kernel(
        const _Float16* __restrict__ X, const _Float16* __restrict__ Wt,
        const float* __restrict__ bias, float* __restrict__ out, int n) {
    __shared__ _Float16 Af[64 * 136];
    __shared__ _Float16 Bt[128 * 136];
    int t = threadIdx.x;
    int r0 = blockIdx.x * 64;

#pragma unroll
    for (int i = 0; i < 4; ++i) {
        int flat = i * 256 + t;
        int r = flat >> 4, k8 = flat & 15;
        half8 v = {0, 0, 0, 0, 0, 0, 0, 0};
        if (r0 + r < n) v = *(const half8*)&X[(size_t)(r0 + r) * 128 + k8 * 8];
        *(half8*)&Af[r * 136 + k8 * 8] = v;
    }
#pragma unroll
    for (int i = 0; i < 8; ++i) {
        int flat = i * 256 + t;
        int c = flat >> 4, k8 = flat & 15;
        *(half8*)&Bt[c * 136 + k8 * 8] = *(const half8*)&Wt[c * 128 + k8 * 8];
    }
    __syncthreads();

    int lane = t & 63, w = t >> 6;
    int m = lane & 15, q = lane >> 4;

    floatx4 acc[8];
#pragma unroll
    for (int nt = 0; nt < 8; ++nt) acc[nt] = (floatx4){0.f, 0.f, 0.f, 0.f};

#pragma unroll
    for (int s = 0; s < 4; ++s) {
        half8 a = *(const half8*)&Af[(w * 16 + m) * 136 + s * 32 + q * 8];
#pragma unroll
        for (int nt = 0; nt < 8; ++nt) {
            half8 b = *(const half8*)&Bt[(nt * 16 + m) * 136 + s * 32 + q * 8];
            acc[nt] = __builtin_amdgcn_mfma_f32_16x16x32_f16(a, b, acc[nt], 0, 0, 0);
        }
    }

    int rowb = r0 + w * 16 + q * 4;
#pragma unroll
    for (int nt = 0; nt < 8; ++nt) {
        int col = nt * 16 + m;
        float bb = bias[col];
#pragma unroll
        for (int r = 0; r < 4; ++r) {
            int gr = rowb + r;
            if (gr < n) out[(size_t)gr * 128 + col] = acc[nt][r] + bb;
        }
    }
}

// One wave per node; lane = 2 f16 features (one dword gather per edge/lane).
// fp32 accumulate; out f16. Edge loop unrolled x4.
__global__ void spmm_kernel(const _Float16* __restrict__ h, const _Float16* __restrict__ xr,
                            const int* __restrict__ row_ptr, const int2* __restrict__ csr,
                            const float* __restrict__ dinv, _Float16* __restrict__ out,
                            int n, int do_relu) {
    int gid = blockIdx.x * blockDim.x + threadIdx.x;
    int node = gid >> 6;
    int lane = gid & 63;
    if (node >= n) return;
    const half2v* hp = (const half2v*)h;
    float di = dinv[node];
    float w = di * di;
    half2v hv = hp[(size_t)node * 64 + lane];
    float accx = (float)hv.x * w, accy = (float)hv.y * w;
    int e = row_ptr[node], eend = row_ptr[node + 1];
    for (; e + 4 <= eend; e += 4) {
        int2 d0 = csr[e], d1 = csr[e + 1], d2 = csr[e + 2], d3 = csr[e + 3];
        half2v v0 = hp[(size_t)d0.x * 64 + lane];
        half2v v1 = hp[(size_t)d1.x * 64 + lane];
        half2v v2 = hp[(size_t)d2.x * 64 + lane];
        half2v v3 = hp[(size_t)d3.x * 64 + lane];
        float n0 = __int_as_float(d0.y), n1 = __int_as_float(d1.y);
        float n2 = __int_as_float(d2.y), n3 = __int_as_float(d3.y);
        accx = fmaf(n0, (float)v0.x, accx); accy = fmaf(n0, (float)v0.y, accy);
        accx = fmaf(n1, (float)v1.x, accx); accy = fmaf(n1, (float)v1.y, accy);
        accx = fmaf(n2, (float)v2.x, accx); accy = fmaf(n2, (float)v2.y, accy);
        accx = fmaf(n3, (float)v3.x, accx); accy = fmaf(n3, (float)v3.y, accy);
    }
    for (; e < eend; ++e) {
        int2 ed = csr[e];
        float nrm = __int_as_float(ed.y);
        half2v v = hp[(size_t)ed.x * 64 + lane];
        accx = fmaf(nrm, (float)v.x, accx);
        accy = fmaf(nrm, (float)v.y, accy);
    }
    if (xr) {
        half2v r = ((const half2v*)xr)[(size_t)node * 64 + lane];
        accx += (float)r.x;
        accy += (float)r.y;
    }
    if (do_relu) {
        accx = fmaxf(accx, 0.f);
        accy = fmaxf(accy, 0.f);
    }
    half2v o;
    o.x = (_Float16)accx;
    o.y = (_Float16)accy;
    ((half2v*)out)[(size_t)node * 64 + lane] = o;
}

extern "C" void kernel_launch(void* const* d_in, const int* in_sizes, int n_in,
                              void* d_out, int out_size, void* d_ws, size_t ws_size,
                              hipStream_t stream) {
    const float* x  = (const float*)d_in[0];
    const int*   ei = (const int*)d_in[1];
    const float* W1 = (const float*)d_in[2];
    const float* R1 = (const float*)d_in[3];
    const float* W2 = (const float*)d_in[4];
    const float* R2 = (const float*)d_in[5];
    const float* W3 = (const float*)d_in[6];
    const float* Wh = (const float*)d_in[7];
    const float* bh = (const float*)d_in[8];
    float* out = (float*)d_out;

    int N = in_sizes[0] / 128;
    int E = in_sizes[1] / 2;

    char* p = (char*)d_ws;
    auto alloc = [&](size_t bytes) {
        char* r = p;
        p += (bytes + 255) & ~(size_t)255;
        return r;
    };
    int*      cnt     = (int*)alloc((size_t)N * 4);
    int*      row_ptr = (int*)alloc((size_t)(N + 1) * 4);
    int*      cursor  = (int*)alloc((size_t)N * 4);
    float*    dinv    = (float*)alloc((size_t)N * 4);
    int*      bsum    = (int*)alloc((size_t)1024 * 4);
    int*      boff    = (int*)alloc((size_t)1024 * 4);
    int2*     csr     = (int2*)alloc((size_t)E * 8);
    _Float16* Wt      = (_Float16*)alloc((size_t)6 * 16384 * 2);
    _Float16* xh      = (_Float16*)alloc((size_t)N * 128 * 2);
    _Float16* B0h     = (_Float16*)alloc((size_t)N * 128 * 2);
    _Float16* B1h     = (_Float16*)alloc((size_t)N * 128 * 2);
    _Float16* B2h     = (_Float16*)alloc((size_t)N * 128 * 2);

    const int* rowi = ei;
    const int* coli = ei + E;

    int nb = (N + SCAN_CHUNK - 1) / SCAN_CHUNK;

    zero_int_kernel<<<(N + 255) / 256, 256, 0, stream>>>(cnt, N);
    hist_kernel<<<(E + 255) / 256, 256, 0, stream>>>(coli, cnt, E);
    dinv_kernel<<<(N + 255) / 256, 256, 0, stream>>>(cnt, dinv, N);
    scan_reduce_kernel<<<nb, 256, 0, stream>>>(cnt, bsum, N);
    scan_bsum_kernel<<<1, 1024, 0, stream>>>(bsum, boff, nb);
    scan_write_kernel<<<nb, 256, 0, stream>>>(cnt, boff, row_ptr, cursor, N, E);
    fill_kernel<<<(E + 255) / 256, 256, 0, stream>>>(rowi, coli, dinv, cursor, csr, E);
    wcvt_kernel<<<96, 256, 0, stream>>>(W1, R1, W2, R2, W3, Wh, Wt);
    cvt_kernel<<<(N * 128 / 4 + 255) / 256, 256, 0, stream>>>(x, xh, N * 128);

    int gb = (N + 63) / 64;
    int sb = (N + 3) / 4;
    _Float16* Wt1 = Wt;
    _Float16* Rt1 = Wt + 16384;
    _Float16* Wt2 = Wt + 2 * 16384;
    _Float16* Rt2 = Wt + 3 * 16384;
    _Float16* Wt3 = Wt + 4 * 16384;
    _Float16* Wth = Wt + 5 * 16384;

    // layer 1: H=B0h, XR=B1h, x1 -> B1h (in-place residual add ok: per-thread RMW)
    gemm_h_kernel<<<gb, 256, 0, stream>>>(xh, Wt1, B0h, N);
    gemm_h_kernel<<<gb, 256, 0, stream>>>(xh, Rt1, B1h, N);
    spmm_kernel<<<sb, 256, 0, stream>>>(B0h, B1h, row_ptr, csr, dinv, B1h, N, 1);
    // layer 2: H=B0h, XR=B2h, x2 -> B2h
    gemm_h_kernel<<<gb, 256, 0, stream>>>(B1h, Wt2, B0h, N);
    gemm_h_kernel<<<gb, 256, 0, stream>>>(B1h, Rt2, B2h, N);
    spmm_kernel<<<sb, 256, 0, stream>>>(B0h, B2h, row_ptr, csr, dinv, B2h, N, 1);
    // layer 3: H=B0h, x3 -> B1h (no residual, no relu)
    gemm_h_kernel<<<gb, 256, 0, stream>>>(B2h, Wt3, B0h, N);
    spmm_kernel<<<sb, 256, 0, stream>>>(B0h, nullptr, row_ptr, csr, dinv, B1h, N, 0);
    // head: out = B1h @ Wh + bh (fp32)
    gemm_f_kernel<<<gb, 256, 0, stream>>>(B1h, Wth, bh, out, N);
}

// Round 5
// 317.201 us; speedup vs baseline: 2.0007x; 1.0718x over previous
//
#include <hip/hip_runtime.h>
#include <hip/hip_bf16.h>

// GCN stack: N=50000 nodes, E=600000 edges, D=128.
//  1. zero cnt; histogram col -> cnt; dinv = rsqrt(cnt+1)
//  2. hierarchical scan -> row_ptr/cursor; fill CSR (src,norm) by dest
//  3. wcvt: weights fp32 [k][c] -> f16 transposed [c][k]
//  4. layers: dual f16-MFMA GEMM (A staged once, W+R passes) + SpMM
//     (16 lanes/row, 4 edges/gather-instr, fp32 accum, shfl_xor reduce)
//
// R1: single-block scan 111us -> hierarchical (634->542)
// R2: fp32 VALU GEMM -> f16 MFMA; SpMM unroll x4 (542->422)
// R3: all activations f16 (gather row 512B->256B) (422->340)
// R4: SpMM 4 edges/instr (16B/lane) + dual-GEMM fusion (cvt folded into L1)

#define SCAN_CHUNK 1024

typedef _Float16 half8 __attribute__((ext_vector_type(8)));
typedef _Float16 half4 __attribute__((ext_vector_type(4)));
typedef float floatx4 __attribute__((ext_vector_type(4)));

__global__ void zero_int_kernel(int* __restrict__ p, int n) {
    int i = blockIdx.x * blockDim.x + threadIdx.x;
    if (i < n) p[i] = 0;
}

__global__ void hist_kernel(const int* __restrict__ col, int* __restrict__ cnt, int E) {
    int i = blockIdx.x * blockDim.x + threadIdx.x;
    if (i < E) atomicAdd(&cnt[col[i]], 1);
}

__global__ void dinv_kernel(const int* __restrict__ cnt, float* __restrict__ dinv, int n) {
    int i = blockIdx.x * blockDim.x + threadIdx.x;
    if (i < n) dinv[i] = rsqrtf((float)(cnt[i] + 1));
}

__global__ __launch_bounds__(256) void scan_reduce_kernel(
        const int* __restrict__ cnt, int* __restrict__ bsum, int n) {
    __shared__ int s[256];
    int b = blockIdx.x, t = threadIdx.x;
    int base = b * SCAN_CHUNK + t * 4;
    int v = 0;
    if (base + 3 < n) {
        int4 q = *(const int4*)&cnt[base];
        v = q.x + q.y + q.z + q.w;
    } else {
        for (int i = 0; i < 4; ++i) if (base + i < n) v += cnt[base + i];
    }
    s[t] = v;
    __syncthreads();
    for (int off = 128; off > 0; off >>= 1) {
        if (t < off) s[t] += s[t + off];
        __syncthreads();
    }
    if (t == 0) bsum[b] = s[0];
}

__global__ __launch_bounds__(1024) void scan_bsum_kernel(
        const int* __restrict__ bsum, int* __restrict__ boff, int nb) {
    __shared__ int s[1024];
    int t = threadIdx.x;
    s[t] = (t < nb) ? bsum[t] : 0;
    __syncthreads();
    for (int off = 1; off < 1024; off <<= 1) {
        int add = (t >= off) ? s[t - off] : 0;
        __syncthreads();
        s[t] += add;
        __syncthreads();
    }
    if (t < nb) boff[t] = (t == 0) ? 0 : s[t - 1];
}

__global__ __launch_bounds__(256) void scan_write_kernel(
        const int* __restrict__ cnt, const int* __restrict__ boff,
        int* __restrict__ row_ptr, int* __restrict__ cursor, int n, int E) {
    __shared__ int s[256];
    int b = blockIdx.x, t = threadIdx.x;
    int base = b * SCAN_CHUNK + t * 4;
    int v[4];
    int sum = 0;
    for (int i = 0; i < 4; ++i) {
        v[i] = (base + i < n) ? cnt[base + i] : 0;
        sum += v[i];
    }
    s[t] = sum;
    __syncthreads();
    for (int off = 1; off < 256; off <<= 1) {
        int add = (t >= off) ? s[t - off] : 0;
        __syncthreads();
        s[t] += add;
        __syncthreads();
    }
    int prefix = boff[b] + ((t == 0) ? 0 : s[t - 1]);
    for (int i = 0; i < 4; ++i) {
        if (base + i < n) {
            row_ptr[base + i] = prefix;
            cursor[base + i] = prefix;
            prefix += v[i];
        }
    }
    if (b == 0 && t == 0) row_ptr[n] = E;
}

__global__ void fill_kernel(const int* __restrict__ row, const int* __restrict__ colv,
                            const float* __restrict__ dinv, int* __restrict__ cursor,
                            int2* __restrict__ csr, int E) {
    int i = blockIdx.x * blockDim.x + threadIdx.x;
    if (i < E) {
        int r = row[i], c = colv[i];
        int p = atomicAdd(&cursor[c], 1);
        float nrm = dinv[r] * dinv[c];
        csr[p] = make_int2(r, __float_as_int(nrm));
    }
}

// All 6 weights: fp32 W[k][c] -> f16 Wt[c][k] (row-major [128][128]).
__global__ __launch_bounds__(256) void wcvt_kernel(
        const float* __restrict__ W1, const float* __restrict__ R1,
        const float* __restrict__ W2, const float* __restrict__ R2,
        const float* __restrict__ W3, const float* __restrict__ Wh,
        _Float16* __restrict__ Wt) {
    __shared__ float tile[32][33];
    int b = blockIdx.x;
    int mat = b >> 4, tl = b & 15;
    const float* W = (mat == 0) ? W1 : (mat == 1) ? R1 : (mat == 2) ? W2
                   : (mat == 3) ? R2 : (mat == 4) ? W3 : Wh;
    _Float16* T = Wt + (size_t)mat * 16384;
    int tr = (tl >> 2) * 32, tc = (tl & 3) * 32;
    int t = threadIdx.x;
    int i = t >> 3, j4 = t & 7;
    float4 v = *(const float4*)&W[(tr + i) * 128 + tc + j4 * 4];
    tile[i][j4 * 4 + 0] = v.x;
    tile[i][j4 * 4 + 1] = v.y;
    tile[i][j4 * 4 + 2] = v.z;
    tile[i][j4 * 4 + 3] = v.w;
    __syncthreads();
    half4 h;
    h.x = (_Float16)tile[j4 * 4 + 0][i];
    h.y = (_Float16)tile[j4 * 4 + 1][i];
    h.z = (_Float16)tile[j4 * 4 + 2][i];
    h.w = (_Float16)tile[j4 * 4 + 3][i];
    *(half4*)&T[(tc + i) * 128 + tr + j4 * 4] = h;
}

// Dual GEMM: outA = X@WA, outB = X@WB. A staged once (fp32->f16 if F32IN),
// A-fragments cached in regs across both B passes (LDS Bt reused).
// Fragment layouts (HW-verified, guide §3): A[m=lane&15][k=quad*8+j],
// B[k=quad*8+j][n=lane&15], C/D col=lane&15 row=quad*4+reg.
template <int F32IN>
__global__ __launch_bounds__(256) void gemm_dual_kernel(
        const void* __restrict__ Xv, const _Float16* __restrict__ WtA,
        const _Float16* __restrict__ WtB, _Float16* __restrict__ outA,
        _Float16* __restrict__ outB, int n) {
    __shared__ _Float16 Af[64 * 136];
    __shared__ _Float16 Bt[128 * 136];
    int t = threadIdx.x;
    int r0 = blockIdx.x * 64;

    if (F32IN) {
        const float* X = (const float*)Xv;
#pragma unroll
        for (int i = 0; i < 8; ++i) {
            int flat = i * 256 + t;
            int r = flat >> 5, c4 = flat & 31;
            float4 v = make_float4(0.f, 0.f, 0.f, 0.f);
            if (r0 + r < n) v = ((const float4*)X)[(size_t)(r0 + r) * 32 + c4];
            half4 h;
            h.x = (_Float16)v.x; h.y = (_Float16)v.y;
            h.z = (_Float16)v.z; h.w = (_Float16)v.w;
            *(half4*)&Af[r * 136 + c4 * 4] = h;
        }
    } else {
        const _Float16* X = (const _Float16*)Xv;
#pragma unroll
        for (int i = 0; i < 4; ++i) {
            int flat = i * 256 + t;
            int r = flat >> 4, k8 = flat & 15;
            half8 v = {0, 0, 0, 0, 0, 0, 0, 0};
            if (r0 + r < n) v = *(const half8*)&X[(size_t)(r0 + r) * 128 + k8 * 8];
            *(half8*)&Af[r * 136 + k8 * 8] = v;
        }
    }
#pragma unroll
    for (int i = 0; i < 8; ++i) {
        int flat = i * 256 + t;
        int c = flat >> 4, k8 = flat & 15;
        *(half8*)&Bt[c * 136 + k8 * 8] = *(const half8*)&WtA[c * 128 + k8 * 8];
    }
    __syncthreads();

    int lane = t & 63, w = t >> 6;
    int m = lane & 15, q = lane >> 4;
    int rowb = r0 + w * 16 + q * 4;

    half8 a[4];
#pragma unroll
    for (int s = 0; s < 4; ++s)
        a[s] = *(const half8*)&Af[(w * 16 + m) * 136 + s * 32 + q * 8];

    floatx4 acc[8];
#pragma unroll
    for (int nt = 0; nt < 8; ++nt) acc[nt] = (floatx4){0.f, 0.f, 0.f, 0.f};
#pragma unroll
    for (int s = 0; s < 4; ++s)
#pragma unroll
        for (int nt = 0; nt < 8; ++nt) {
            half8 b = *(const half8*)&Bt[(nt * 16 + m) * 136 + s * 32 + q * 8];
            acc[nt] = __builtin_amdgcn_mfma_f32_16x16x32_f16(a[s], b, acc[nt], 0, 0, 0);
        }
    __syncthreads();
    // restage Bt with WtB; epilogue-A global stores overlap the staging
#pragma unroll
    for (int i = 0; i < 8; ++i) {
        int flat = i * 256 + t;
        int c = flat >> 4, k8 = flat & 15;
        *(half8*)&Bt[c * 136 + k8 * 8] = *(const half8*)&WtB[c * 128 + k8 * 8];
    }
#pragma unroll
    for (int nt = 0; nt < 8; ++nt) {
        int col = nt * 16 + m;
#pragma unroll
        for (int r = 0; r < 4; ++r) {
            int gr = rowb + r;
            if (gr < n) outA[(size_t)gr * 128 + col] = (_Float16)acc[nt][r];
        }
    }
    __syncthreads();

#pragma unroll
    for (int nt = 0; nt < 8; ++nt) acc[nt] = (floatx4){0.f, 0.f, 0.f, 0.f};
#pragma unroll
    for (int s = 0; s < 4; ++s)
#pragma unroll
        for (int nt = 0; nt < 8; ++nt) {
            half8 b = *(const half8*)&Bt[(nt * 16 + m) * 136 + s * 32 + q * 8];
            acc[nt] = __builtin_amdgcn_mfma_f32_16x16x32_f16(a[s], b, acc[nt], 0, 0, 0);
        }
#pragma unroll
    for (int nt = 0; nt < 8; ++nt) {
        int col = nt * 16 + m;
#pragma unroll
        for (int r = 0; r < 4; ++r) {
            int gr = rowb + r;
            if (gr < n) outB[(size_t)gr * 128 + col] = (_Float16)acc[nt][r];
        }
    }
}

// Single GEMM, f16 in / f16 out.
__global__ __launch_bounds__(256) void gemm_h_kernel(
        const _Float16* __restrict__ X, const _Float16* __restrict__ Wt,
        _Float16* __restrict__ out, int n) {
    __shared__ _Float16 Af[64 * 136];
    __shared__ _Float16 Bt[128 * 136];
    int t = threadIdx.x;
    int r0 = blockIdx.x * 64;

#pragma unroll
    for (int i = 0; i < 4; ++i) {
        int flat = i * 256 + t;
        int r = flat >> 4, k8 = flat & 15;
        half8 v = {0, 0, 0, 0, 0, 0, 0, 0};
        if (r0 + r < n) v = *(const half8*)&X[(size_t)(r0 + r) * 128 + k8 * 8];
        *(half8*)&Af[r * 136 + k8 * 8] = v;
    }
#pragma unroll
    for (int i = 0; i < 8; ++i) {
        int flat = i * 256 + t;
        int c = flat >> 4, k8 = flat & 15;
        *(half8*)&Bt[c * 136 + k8 * 8] = *(const half8*)&Wt[c * 128 + k8 * 8];
    }
    __syncthreads();

    int lane = t & 63, w = t >> 6;
    int m = lane & 15, q = lane >> 4;

    floatx4 acc[8];
#pragma unroll
    for (int nt = 0; nt < 8; ++nt) acc[nt] = (floatx4){0.f, 0.f, 0.f, 0.f};

#pragma unroll
    for (int s = 0; s < 4; ++s) {
        half8 a = *(const half8*)&Af[(w * 16 + m) * 136 + s * 32 + q * 8];
#pragma unroll
        for (int nt = 0; nt < 8; ++nt) {
            half8 b = *(const half8*)&Bt[(nt * 16 + m) * 136 + s * 32 + q * 8];
            acc[nt] = __builtin_amdgcn_mfma_f32_16x16x32_f16(a, b, acc[nt], 0, 0, 0);
        }
    }

    int rowb = r0 + w * 16 + q * 4;
#pragma unroll
    for (int nt = 0; nt < 8; ++nt) {
        int col = nt * 16 + m;
#pragma unroll
        for (int r = 0; r < 4; ++r) {
            int gr = rowb + r;
            if (gr < n) out[(size_t)gr * 128 + col] = (_Float16)acc[nt][r];
        }
    }
}

// Head: f16 in, fp32 out + bias.
__global__ __launch_bounds__(256) void gemm_f_kernel(
        const _Float16* __restrict__ X, const _Float16* __restrict__ Wt,
        const float* __restrict__ bias, float* __restrict__ out, int n) {
    __shared__ _Float16 Af[64 * 136];
    __shared__ _Float16 Bt[128 * 136];
    int t = threadIdx.x;
    int r0 = blockIdx.x * 64;

#pragma unroll
    for (int i = 0; i < 4; ++i) {
        int flat = i * 256 + t;
        int r = flat >> 4, k8 = flat & 15;
        half8 v = {0, 0, 0, 0, 0, 0, 0, 0};
        if (r0 + r < n) v = *(const half8*)&X[(size_t)(r0 + r) * 128 + k8 * 8];
        *(half8*)&Af[r * 136 + k8 * 8] = v;
    }
#pragma unroll
    for (int i = 0; i < 8; ++i) {
        int flat = i * 256 + t;
        int c = flat >> 4, k8 = flat & 15;
        *(half8*)&Bt[c * 136 + k8 * 8] = *(const half8*)&Wt[c * 128 + k8 * 8];
    }
    __syncthreads();

    int lane = t & 63, w = t >> 6;
    int m = lane & 15, q = lane >> 4;

    floatx4 acc[8];
#pragma unroll
    for (int nt = 0; nt < 8; ++nt) acc[nt] = (floatx4){0.f, 0.f, 0.f, 0.f};

#pragma unroll
    for (int s = 0; s < 4; ++s) {
        half8 a = *(const half8*)&Af[(w * 16 + m) * 136 + s * 32 + q * 8];
#pragma unroll
        for (int nt = 0; nt < 8; ++nt) {
            half8 b = *(const half8*)&Bt[(nt * 16 + m) * 136 + s * 32 + q * 8];
            acc[nt] = __builtin_amdgcn_mfma_f32_16x16x32_f16(a, b, acc[nt], 0, 0, 0);
        }
    }

    int rowb = r0 + w * 16 + q * 4;
#pragma unroll
    for (int nt = 0; nt < 8; ++nt) {
        int col = nt * 16 + m;
        float bb = bias[col];
#pragma unroll
        for (int r = 0; r < 4; ++r) {
            int gr = rowb + r;
            if (gr < n) out[(size_t)gr * 128 + col] = acc[nt][r] + bb;
        }
    }
}

// SpMM: one wave per node. Wave split into 4 sub-groups of 16 lanes;
// sub-group handles one edge per gather instr (16 lanes x 16B = 256B row).
// Unrolled x4 -> 16 edges in flight/wave. fp32 accum (8/lane), shfl_xor
// reduce across sub-groups, epilogue on sub==0 lanes.
__global__ void spmm_kernel(const _Float16* __restrict__ h, const _Float16* __restrict__ xr,
                            const int* __restrict__ row_ptr, const int2* __restrict__ csr,
                            const float* __restrict__ dinv, _Float16* __restrict__ out,
                            int n, int do_relu) {
    int gid = blockIdx.x * blockDim.x + threadIdx.x;
    int node = gid >> 6;
    int lane = gid & 63;
    if (node >= n) return;
    int sub = lane >> 4;   // which edge in group of 4
    int fl = lane & 15;    // feature slice: 8 f16 at fl*8
    const half8* hp8 = (const half8*)h;

    float acc[8];
#pragma unroll
    for (int j = 0; j < 8; ++j) acc[j] = 0.f;

    int e0 = row_ptr[node], e1 = row_ptr[node + 1];
    int e = e0;
    for (; e + 16 <= e1; e += 16) {
        int2 d0 = csr[e + sub];
        int2 d1 = csr[e + 4 + sub];
        int2 d2 = csr[e + 8 + sub];
        int2 d3 = csr[e + 12 + sub];
        half8 v0 = hp8[(size_t)d0.x * 16 + fl];
        half8 v1 = hp8[(size_t)d1.x * 16 + fl];
        half8 v2 = hp8[(size_t)d2.x * 16 + fl];
        half8 v3 = hp8[(size_t)d3.x * 16 + fl];
        float n0 = __int_as_float(d0.y), n1 = __int_as_float(d1.y);
        float n2 = __int_as_float(d2.y), n3 = __int_as_float(d3.y);
#pragma unroll
        for (int j = 0; j < 8; ++j) {
            acc[j] = fmaf(n0, (float)v0[j], acc[j]);
            acc[j] = fmaf(n1, (float)v1[j], acc[j]);
            acc[j] = fmaf(n2, (float)v2[j], acc[j]);
            acc[j] = fmaf(n3, (float)v3[j], acc[j]);
        }
    }
    for (; e < e1; e += 4) {
        int idx = e + sub;
        int act = idx < e1;
        int cidx = act ? idx : (e1 - 1);
        int2 d = csr[cidx];
        float nrm = act ? __int_as_float(d.y) : 0.f;
        half8 v = hp8[(size_t)d.x * 16 + fl];
#pragma unroll
        for (int j = 0; j < 8; ++j) acc[j] = fmaf(nrm, (float)v[j], acc[j]);
    }
    // reduce across the 4 sub-groups (lanes with equal fl)
#pragma unroll
    for (int j = 0; j < 8; ++j) {
        acc[j] += __shfl_xor(acc[j], 16, 64);
        acc[j] += __shfl_xor(acc[j], 32, 64);
    }

    float di = dinv[node];
    if (sub == 0) {
        float w = di * di;
        half8 hv = hp8[(size_t)node * 16 + fl];
#pragma unroll
        for (int j = 0; j < 8; ++j) acc[j] = fmaf(w, (float)hv[j], acc[j]);
        if (xr) {
            half8 r = ((const half8*)xr)[(size_t)node * 16 + fl];
#pragma unroll
            for (int j = 0; j < 8; ++j) acc[j] += (float)r[j];
        }
        if (do_relu) {
#pragma unroll
            for (int j = 0; j < 8; ++j) acc[j] = fmaxf(acc[j], 0.f);
        }
        half8 o;
#pragma unroll
        for (int j = 0; j < 8; ++j) o[j] = (_Float16)acc[j];
        ((half8*)out)[(size_t)node * 16 + fl] = o;
    }
}

extern "C" void kernel_launch(void* const* d_in, const int* in_sizes, int n_in,
                              void* d_out, int out_size, void* d_ws, size_t ws_size,
                              hipStream_t stream) {
    const float* x  = (const float*)d_in[0];
    const int*   ei = (const int*)d_in[1];
    const float* W1 = (const float*)d_in[2];
    const float* R1 = (const float*)d_in[3];
    const float* W2 = (const float*)d_in[4];
    const float* R2 = (const float*)d_in[5];
    const float* W3 = (const float*)d_in[6];
    const float* Wh = (const float*)d_in[7];
    const float* bh = (const float*)d_in[8];
    float* out = (float*)d_out;

    int N = in_sizes[0] / 128;
    int E = in_sizes[1] / 2;

    char* p = (char*)d_ws;
    auto alloc = [&](size_t bytes) {
        char* r = p;
        p += (bytes + 255) & ~(size_t)255;
        return r;
    };
    int*      cnt     = (int*)alloc((size_t)N * 4);
    int*      row_ptr = (int*)alloc((size_t)(N + 1) * 4);
    int*      cursor  = (int*)alloc((size_t)N * 4);
    float*    dinv    = (float*)alloc((size_t)N * 4);
    int*      bsum    = (int*)alloc((size_t)1024 * 4);
    int*      boff    = (int*)alloc((size_t)1024 * 4);
    int2*     csr     = (int2*)alloc((size_t)E * 8);
    _Float16* Wt      = (_Float16*)alloc((size_t)6 * 16384 * 2);
    _Float16* B0h     = (_Float16*)alloc((size_t)N * 128 * 2);
    _Float16* B1h     = (_Float16*)alloc((size_t)N * 128 * 2);
    _Float16* B2h     = (_Float16*)alloc((size_t)N * 128 * 2);

    const int* rowi = ei;
    const int* coli = ei + E;

    int nb = (N + SCAN_CHUNK - 1) / SCAN_CHUNK;

    zero_int_kernel<<<(N + 255) / 256, 256, 0, stream>>>(cnt, N);
    hist_kernel<<<(E + 255) / 256, 256, 0, stream>>>(coli, cnt, E);
    dinv_kernel<<<(N + 255) / 256, 256, 0, stream>>>(cnt, dinv, N);
    scan_reduce_kernel<<<nb, 256, 0, stream>>>(cnt, bsum, N);
    scan_bsum_kernel<<<1, 1024, 0, stream>>>(bsum, boff, nb);
    scan_write_kernel<<<nb, 256, 0, stream>>>(cnt, boff, row_ptr, cursor, N, E);
    fill_kernel<<<(E + 255) / 256, 256, 0, stream>>>(rowi, coli, dinv, cursor, csr, E);
    wcvt_kernel<<<96, 256, 0, stream>>>(W1, R1, W2, R2, W3, Wh, Wt);

    int gb = (N + 63) / 64;
    int sb = (N + 3) / 4;
    _Float16* Wt1 = Wt;
    _Float16* Rt1 = Wt + 16384;
    _Float16* Wt2 = Wt + 2 * 16384;
    _Float16* Rt2 = Wt + 3 * 16384;
    _Float16* Wt3 = Wt + 4 * 16384;
    _Float16* Wth = Wt + 5 * 16384;

    // layer 1: H=B0h, XR=B1h (fp32 x converted in staging), x1 -> B1h
    gemm_dual_kernel<1><<<gb, 256, 0, stream>>>(x, Wt1, Rt1, B0h, B1h, N);
    spmm_kernel<<<sb, 256, 0, stream>>>(B0h, B1h, row_ptr, csr, dinv, B1h, N, 1);
    // layer 2: H=B0h, XR=B2h, x2 -> B2h
    gemm_dual_kernel<0><<<gb, 256, 0, stream>>>(B1h, Wt2, Rt2, B0h, B2h, N);
    spmm_kernel<<<sb, 256, 0, stream>>>(B0h, B2h, row_ptr, csr, dinv, B2h, N, 1);
    // layer 3: H=B0h, x3 -> B1h (no residual, no relu)
    gemm_h_kernel<<<gb, 256, 0, stream>>>(B2h, Wt3, B0h, N);
    spmm_kernel<<<sb, 256, 0, stream>>>(B0h, nullptr, row_ptr, csr, dinv, B1h, N, 0);
    // head: out = B1h @ Wh + bh (fp32)
    gemm_f_kernel<<<gb, 256, 0, stream>>>(B1h, Wth, bh, out, N);
}

// Round 6
// 315.657 us; speedup vs baseline: 2.0105x; 1.0049x over previous
//
#include <hip/hip_runtime.h>
#include <hip/hip_bf16.h>

// GCN stack: N=50000 nodes, E=600000 edges, D=128.
//  1. zero cnt; histogram col -> cnt
//  2. hierarchical scan -> row_ptr/cursor (+dinv folded in); fill CSR by dest
//  3. wcvt: W1,R1,W2,R2 fp32 [k][c] -> f16 transposed [c][k];
//     wc: Wc = W3@Wh (fp32 accum) -> f16 transposed (head folded by linearity:
//     (A@(x2@W3))@Wh + bh == A@(x2@Wc) + bh)
//  4. L1/L2: dual f16-MFMA GEMM (A staged once, W+R passes) + SpMM relu
//     L3+head: gemm_h(Wc) + SpMM writing fp32 + bias into d_out
//
// R1: single-block scan 111us -> hierarchical (634->542)
// R2: fp32 VALU GEMM -> f16 MFMA; SpMM unroll x4 (542->422)
// R3: all activations f16 (gather row 512B->256B) (422->340)
// R4: SpMM 4 edges/instr (16B/lane) + dual-GEMM fusion (340->317)
// R5: head GEMM folded into Wc=W3@Wh; final SpMM -> fp32+bias; dinv folded
//     into scan_write. 16 -> 13 dispatches.

#define SCAN_CHUNK 1024

typedef _Float16 half8 __attribute__((ext_vector_type(8)));
typedef _Float16 half4 __attribute__((ext_vector_type(4)));
typedef float floatx4 __attribute__((ext_vector_type(4)));

__global__ void zero_int_kernel(int* __restrict__ p, int n) {
    int i = blockIdx.x * blockDim.x + threadIdx.x;
    if (i < n) p[i] = 0;
}

__global__ void hist_kernel(const int* __restrict__ col, int* __restrict__ cnt, int E) {
    int i = blockIdx.x * blockDim.x + threadIdx.x;
    if (i < E) atomicAdd(&cnt[col[i]], 1);
}

__global__ __launch_bounds__(256) void scan_reduce_kernel(
        const int* __restrict__ cnt, int* __restrict__ bsum, int n) {
    __shared__ int s[256];
    int b = blockIdx.x, t = threadIdx.x;
    int base = b * SCAN_CHUNK + t * 4;
    int v = 0;
    if (base + 3 < n) {
        int4 q = *(const int4*)&cnt[base];
        v = q.x + q.y + q.z + q.w;
    } else {
        for (int i = 0; i < 4; ++i) if (base + i < n) v += cnt[base + i];
    }
    s[t] = v;
    __syncthreads();
    for (int off = 128; off > 0; off >>= 1) {
        if (t < off) s[t] += s[t + off];
        __syncthreads();
    }
    if (t == 0) bsum[b] = s[0];
}

__global__ __launch_bounds__(1024) void scan_bsum_kernel(
        const int* __restrict__ bsum, int* __restrict__ boff, int nb) {
    __shared__ int s[1024];
    int t = threadIdx.x;
    s[t] = (t < nb) ? bsum[t] : 0;
    __syncthreads();
    for (int off = 1; off < 1024; off <<= 1) {
        int add = (t >= off) ? s[t - off] : 0;
        __syncthreads();
        s[t] += add;
        __syncthreads();
    }
    if (t < nb) boff[t] = (t == 0) ? 0 : s[t - 1];
}

// scan chunk write + dinv = rsqrt(cnt+1) folded in (reads cnt anyway)
__global__ __launch_bounds__(256) void scan_write_kernel(
        const int* __restrict__ cnt, const int* __restrict__ boff,
        int* __restrict__ row_ptr, int* __restrict__ cursor,
        float* __restrict__ dinv, int n, int E) {
    __shared__ int s[256];
    int b = blockIdx.x, t = threadIdx.x;
    int base = b * SCAN_CHUNK + t * 4;
    int v[4];
    int sum = 0;
    for (int i = 0; i < 4; ++i) {
        v[i] = (base + i < n) ? cnt[base + i] : 0;
        sum += v[i];
    }
    s[t] = sum;
    __syncthreads();
    for (int off = 1; off < 256; off <<= 1) {
        int add = (t >= off) ? s[t - off] : 0;
        __syncthreads();
        s[t] += add;
        __syncthreads();
    }
    int prefix = boff[b] + ((t == 0) ? 0 : s[t - 1]);
    for (int i = 0; i < 4; ++i) {
        if (base + i < n) {
            row_ptr[base + i] = prefix;
            cursor[base + i] = prefix;
            dinv[base + i] = rsqrtf((float)(v[i] + 1));
            prefix += v[i];
        }
    }
    if (b == 0 && t == 0) row_ptr[n] = E;
}

__global__ void fill_kernel(const int* __restrict__ row, const int* __restrict__ colv,
                            const float* __restrict__ dinv, int* __restrict__ cursor,
                            int2* __restrict__ csr, int E) {
    int i = blockIdx.x * blockDim.x + threadIdx.x;
    if (i < E) {
        int r = row[i], c = colv[i];
        int p = atomicAdd(&cursor[c], 1);
        float nrm = dinv[r] * dinv[c];
        csr[p] = make_int2(r, __float_as_int(nrm));
    }
}

// W1,R1,W2,R2: fp32 W[k][c] -> f16 Wt[c][k] (row-major [128][128]). 64 blocks.
__global__ __launch_bounds__(256) void wcvt_kernel(
        const float* __restrict__ W1, const float* __restrict__ R1,
        const float* __restrict__ W2, const float* __restrict__ R2,
        _Float16* __restrict__ Wt) {
    __shared__ float tile[32][33];
    int b = blockIdx.x;
    int mat = b >> 4, tl = b & 15;
    const float* W = (mat == 0) ? W1 : (mat == 1) ? R1 : (mat == 2) ? W2 : R2;
    _Float16* T = Wt + (size_t)mat * 16384;
    int tr = (tl >> 2) * 32, tc = (tl & 3) * 32;
    int t = threadIdx.x;
    int i = t >> 3, j4 = t & 7;
    float4 v = *(const float4*)&W[(tr + i) * 128 + tc + j4 * 4];
    tile[i][j4 * 4 + 0] = v.x;
    tile[i][j4 * 4 + 1] = v.y;
    tile[i][j4 * 4 + 2] = v.z;
    tile[i][j4 * 4 + 3] = v.w;
    __syncthreads();
    half4 h;
    h.x = (_Float16)tile[j4 * 4 + 0][i];
    h.y = (_Float16)tile[j4 * 4 + 1][i];
    h.z = (_Float16)tile[j4 * 4 + 2][i];
    h.w = (_Float16)tile[j4 * 4 + 3][i];
    *(half4*)&T[(tc + i) * 128 + tr + j4 * 4] = h;
}

// Wc = W3 @ Wh (fp32 accum), stored f16 transposed: Wtc[c][k] = sum_j W3[k][j]*Wh[j][c].
// 16 blocks x 256 thr; block b owns c = b*8..b*8+7; thread computes 4 k's.
__global__ __launch_bounds__(256) void wc_kernel(
        const float* __restrict__ W3, const float* __restrict__ Wh,
        _Float16* __restrict__ Wtc) {
    int b = blockIdx.x, t = threadIdx.x;
    int c = b * 8 + (t >> 5);
    int k0 = (t & 31) * 4;
    float acc0 = 0.f, acc1 = 0.f, acc2 = 0.f, acc3 = 0.f;
    for (int j = 0; j < 128; ++j) {
        float wh = Wh[j * 128 + c];
        acc0 = fmaf(W3[(k0 + 0) * 128 + j], wh, acc0);
        acc1 = fmaf(W3[(k0 + 1) * 128 + j], wh, acc1);
        acc2 = fmaf(W3[(k0 + 2) * 128 + j], wh, acc2);
        acc3 = fmaf(W3[(k0 + 3) * 128 + j], wh, acc3);
    }
    half4 h;
    h.x = (_Float16)acc0; h.y = (_Float16)acc1;
    h.z = (_Float16)acc2; h.w = (_Float16)acc3;
    *(half4*)&Wtc[c * 128 + k0] = h;
}

// Dual GEMM: outA = X@WA, outB = X@WB. A staged once (fp32->f16 if F32IN),
// A-fragments cached in regs across both B passes (LDS Bt reused).
// Fragment layouts (HW-verified, guide §3): A[m=lane&15][k=quad*8+j],
// B[k=quad*8+j][n=lane&15], C/D col=lane&15 row=quad*4+reg.
template <int F32IN>
__global__ __launch_bounds__(256) void gemm_dual_kernel(
        const void* __restrict__ Xv, const _Float16* __restrict__ WtA,
        const _Float16* __restrict__ WtB, _Float16* __restrict__ outA,
        _Float16* __restrict__ outB, int n) {
    __shared__ _Float16 Af[64 * 136];
    __shared__ _Float16 Bt[128 * 136];
    int t = threadIdx.x;
    int r0 = blockIdx.x * 64;

    if (F32IN) {
        const float* X = (const float*)Xv;
#pragma unroll
        for (int i = 0; i < 8; ++i) {
            int flat = i * 256 + t;
            int r = flat >> 5, c4 = flat & 31;
            float4 v = make_float4(0.f, 0.f, 0.f, 0.f);
            if (r0 + r < n) v = ((const float4*)X)[(size_t)(r0 + r) * 32 + c4];
            half4 h;
            h.x = (_Float16)v.x; h.y = (_Float16)v.y;
            h.z = (_Float16)v.z; h.w = (_Float16)v.w;
            *(half4*)&Af[r * 136 + c4 * 4] = h;
        }
    } else {
        const _Float16* X = (const _Float16*)Xv;
#pragma unroll
        for (int i = 0; i < 4; ++i) {
            int flat = i * 256 + t;
            int r = flat >> 4, k8 = flat & 15;
            half8 v = {0, 0, 0, 0, 0, 0, 0, 0};
            if (r0 + r < n) v = *(const half8*)&X[(size_t)(r0 + r) * 128 + k8 * 8];
            *(half8*)&Af[r * 136 + k8 * 8] = v;
        }
    }
#pragma unroll
    for (int i = 0; i < 8; ++i) {
        int flat = i * 256 + t;
        int c = flat >> 4, k8 = flat & 15;
        *(half8*)&Bt[c * 136 + k8 * 8] = *(const half8*)&WtA[c * 128 + k8 * 8];
    }
    __syncthreads();

    int lane = t & 63, w = t >> 6;
    int m = lane & 15, q = lane >> 4;
    int rowb = r0 + w * 16 + q * 4;

    half8 a[4];
#pragma unroll
    for (int s = 0; s < 4; ++s)
        a[s] = *(const half8*)&Af[(w * 16 + m) * 136 + s * 32 + q * 8];

    floatx4 acc[8];
#pragma unroll
    for (int nt = 0; nt < 8; ++nt) acc[nt] = (floatx4){0.f, 0.f, 0.f, 0.f};
#pragma unroll
    for (int s = 0; s < 4; ++s)
#pragma unroll
        for (int nt = 0; nt < 8; ++nt) {
            half8 b = *(const half8*)&Bt[(nt * 16 + m) * 136 + s * 32 + q * 8];
            acc[nt] = __builtin_amdgcn_mfma_f32_16x16x32_f16(a[s], b, acc[nt], 0, 0, 0);
        }
    __syncthreads();
    // restage Bt with WtB; epilogue-A global stores overlap the staging
#pragma unroll
    for (int i = 0; i < 8; ++i) {
        int flat = i * 256 + t;
        int c = flat >> 4, k8 = flat & 15;
        *(half8*)&Bt[c * 136 + k8 * 8] = *(const half8*)&WtB[c * 128 + k8 * 8];
    }
#pragma unroll
    for (int nt = 0; nt < 8; ++nt) {
        int col = nt * 16 + m;
#pragma unroll
        for (int r = 0; r < 4; ++r) {
            int gr = rowb + r;
            if (gr < n) outA[(size_t)gr * 128 + col] = (_Float16)acc[nt][r];
        }
    }
    __syncthreads();

#pragma unroll
    for (int nt = 0; nt < 8; ++nt) acc[nt] = (floatx4){0.f, 0.f, 0.f, 0.f};
#pragma unroll
    for (int s = 0; s < 4; ++s)
#pragma unroll
        for (int nt = 0; nt < 8; ++nt) {
            half8 b = *(const half8*)&Bt[(nt * 16 + m) * 136 + s * 32 + q * 8];
            acc[nt] = __builtin_amdgcn_mfma_f32_16x16x32_f16(a[s], b, acc[nt], 0, 0, 0);
        }
#pragma unroll
    for (int nt = 0; nt < 8; ++nt) {
        int col = nt * 16 + m;
#pragma unroll
        for (int r = 0; r < 4; ++r) {
            int gr = rowb + r;
            if (gr < n) outB[(size_t)gr * 128 + col] = (_Float16)acc[nt][r];
        }
    }
}

// Single GEMM, f16 in / f16 out.
__global__ __launch_bounds__(256) void gemm_h_kernel(
        const _Float16* __restrict__ X, const _Float16* __restrict__ Wt,
        _Float16* __restrict__ out, int n) {
    __shared__ _Float16 Af[64 * 136];
    __shared__ _Float16 Bt[128 * 136];
    int t = threadIdx.x;
    int r0 = blockIdx.x * 64;

#pragma unroll
    for (int i = 0; i < 4; ++i) {
        int flat = i * 256 + t;
        int r = flat >> 4, k8 = flat & 15;
        half8 v = {0, 0, 0, 0, 0, 0, 0, 0};
        if (r0 + r < n) v = *(const half8*)&X[(size_t)(r0 + r) * 128 + k8 * 8];
        *(half8*)&Af[r * 136 + k8 * 8] = v;
    }
#pragma unroll
    for (int i = 0; i < 8; ++i) {
        int flat = i * 256 + t;
        int c = flat >> 4, k8 = flat & 15;
        *(half8*)&Bt[c * 136 + k8 * 8] = *(const half8*)&Wt[c * 128 + k8 * 8];
    }
    __syncthreads();

    int lane = t & 63, w = t >> 6;
    int m = lane & 15, q = lane >> 4;

    floatx4 acc[8];
#pragma unroll
    for (int nt = 0; nt < 8; ++nt) acc[nt] = (floatx4){0.f, 0.f, 0.f, 0.f};

#pragma unroll
    for (int s = 0; s < 4; ++s) {
        half8 a = *(const half8*)&Af[(w * 16 + m) * 136 + s * 32 + q * 8];
#pragma unroll
        for (int nt = 0; nt < 8; ++nt) {
            half8 b = *(const half8*)&Bt[(nt * 16 + m) * 136 + s * 32 + q * 8];
            acc[nt] = __builtin_amdgcn_mfma_f32_16x16x32_f16(a, b, acc[nt], 0, 0, 0);
        }
    }

    int rowb = r0 + w * 16 + q * 4;
#pragma unroll
    for (int nt = 0; nt < 8; ++nt) {
        int col = nt * 16 + m;
#pragma unroll
        for (int r = 0; r < 4; ++r) {
            int gr = rowb + r;
            if (gr < n) out[(size_t)gr * 128 + col] = (_Float16)acc[nt][r];
        }
    }
}

// SpMM: one wave per node, 4 sub-groups x 16 lanes; sub handles one edge per
// gather instr (16 lanes x 16B = 256B row); unroll x4 -> 16 edges in flight.
// fp32 accum (8/lane), shfl_xor reduce across subs, epilogue on sub==0.
// FINAL: write fp32 + bias into d_out (head folded); else f16 (+xr residual).
template <int RELU, int FINAL>
__global__ void spmm_kernel(const _Float16* __restrict__ h, const _Float16* __restrict__ xr,
                            const int* __restrict__ row_ptr, const int2* __restrict__ csr,
                            const float* __restrict__ dinv, _Float16* __restrict__ outh,
                            float* __restrict__ outf, const float* __restrict__ bias,
                            int n) {
    int gid = blockIdx.x * blockDim.x + threadIdx.x;
    int node = gid >> 6;
    int lane = gid & 63;
    if (node >= n) return;
    int sub = lane >> 4;   // which edge in group of 4
    int fl = lane & 15;    // feature slice: 8 f16 at fl*8
    const half8* hp8 = (const half8*)h;

    float acc[8];
#pragma unroll
    for (int j = 0; j < 8; ++j) acc[j] = 0.f;

    int e0 = row_ptr[node], e1 = row_ptr[node + 1];
    int e = e0;
    for (; e + 16 <= e1; e += 16) {
        int2 d0 = csr[e + sub];
        int2 d1 = csr[e + 4 + sub];
        int2 d2 = csr[e + 8 + sub];
        int2 d3 = csr[e + 12 + sub];
        half8 v0 = hp8[(size_t)d0.x * 16 + fl];
        half8 v1 = hp8[(size_t)d1.x * 16 + fl];
        half8 v2 = hp8[(size_t)d2.x * 16 + fl];
        half8 v3 = hp8[(size_t)d3.x * 16 + fl];
        float n0 = __int_as_float(d0.y), n1 = __int_as_float(d1.y);
        float n2 = __int_as_float(d2.y), n3 = __int_as_float(d3.y);
#pragma unroll
        for (int j = 0; j < 8; ++j) {
            acc[j] = fmaf(n0, (float)v0[j], acc[j]);
            acc[j] = fmaf(n1, (float)v1[j], acc[j]);
            acc[j] = fmaf(n2, (float)v2[j], acc[j]);
            acc[j] = fmaf(n3, (float)v3[j], acc[j]);
        }
    }
    for (; e < e1; e += 4) {
        int idx = e + sub;
        int act = idx < e1;
        int cidx = act ? idx : (e1 - 1);
        int2 d = csr[cidx];
        float nrm = act ? __int_as_float(d.y) : 0.f;
        half8 v = hp8[(size_t)d.x * 16 + fl];
#pragma unroll
        for (int j = 0; j < 8; ++j) acc[j] = fmaf(nrm, (float)v[j], acc[j]);
    }
    // reduce across the 4 sub-groups (lanes with equal fl)
#pragma unroll
    for (int j = 0; j < 8; ++j) {
        acc[j] += __shfl_xor(acc[j], 16, 64);
        acc[j] += __shfl_xor(acc[j], 32, 64);
    }

    float di = dinv[node];
    if (sub == 0) {
        float w = di * di;
        half8 hv = hp8[(size_t)node * 16 + fl];
#pragma unroll
        for (int j = 0; j < 8; ++j) acc[j] = fmaf(w, (float)hv[j], acc[j]);
        if (!FINAL && xr) {
            half8 r = ((const half8*)xr)[(size_t)node * 16 + fl];
#pragma unroll
            for (int j = 0; j < 8; ++j) acc[j] += (float)r[j];
        }
        if (RELU) {
#pragma unroll
            for (int j = 0; j < 8; ++j) acc[j] = fmaxf(acc[j], 0.f);
        }
        if (FINAL) {
            float4 b0 = *(const float4*)&bias[fl * 8];
            float4 b1 = *(const float4*)&bias[fl * 8 + 4];
            float4 o0 = make_float4(acc[0] + b0.x, acc[1] + b0.y,
                                    acc[2] + b0.z, acc[3] + b0.w);
            float4 o1 = make_float4(acc[4] + b1.x, acc[5] + b1.y,
                                    acc[6] + b1.z, acc[7] + b1.w);
            ((float4*)outf)[(size_t)node * 32 + fl * 2] = o0;
            ((float4*)outf)[(size_t)node * 32 + fl * 2 + 1] = o1;
        } else {
            half8 o;
#pragma unroll
            for (int j = 0; j < 8; ++j) o[j] = (_Float16)acc[j];
            ((half8*)outh)[(size_t)node * 16 + fl] = o;
        }
    }
}

extern "C" void kernel_launch(void* const* d_in, const int* in_sizes, int n_in,
                              void* d_out, int out_size, void* d_ws, size_t ws_size,
                              hipStream_t stream) {
    const float* x  = (const float*)d_in[0];
    const int*   ei = (const int*)d_in[1];
    const float* W1 = (const float*)d_in[2];
    const float* R1 = (const float*)d_in[3];
    const float* W2 = (const float*)d_in[4];
    const float* R2 = (const float*)d_in[5];
    const float* W3 = (const float*)d_in[6];
    const float* Wh = (const float*)d_in[7];
    const float* bh = (const float*)d_in[8];
    float* out = (float*)d_out;

    int N = in_sizes[0] / 128;
    int E = in_sizes[1] / 2;

    char* p = (char*)d_ws;
    auto alloc = [&](size_t bytes) {
        char* r = p;
        p += (bytes + 255) & ~(size_t)255;
        return r;
    };
    int*      cnt     = (int*)alloc((size_t)N * 4);
    int*      row_ptr = (int*)alloc((size_t)(N + 1) * 4);
    int*      cursor  = (int*)alloc((size_t)N * 4);
    float*    dinv    = (float*)alloc((size_t)N * 4);
    int*      bsum    = (int*)alloc((size_t)1024 * 4);
    int*      boff    = (int*)alloc((size_t)1024 * 4);
    int2*     csr     = (int2*)alloc((size_t)E * 8);
    _Float16* Wt      = (_Float16*)alloc((size_t)5 * 16384 * 2);
    _Float16* B0h     = (_Float16*)alloc((size_t)N * 128 * 2);
    _Float16* B1h     = (_Float16*)alloc((size_t)N * 128 * 2);
    _Float16* B2h     = (_Float16*)alloc((size_t)N * 128 * 2);

    const int* rowi = ei;
    const int* coli = ei + E;

    int nb = (N + SCAN_CHUNK - 1) / SCAN_CHUNK;

    zero_int_kernel<<<(N + 255) / 256, 256, 0, stream>>>(cnt, N);
    hist_kernel<<<(E + 255) / 256, 256, 0, stream>>>(coli, cnt, E);
    scan_reduce_kernel<<<nb, 256, 0, stream>>>(cnt, bsum, N);
    scan_bsum_kernel<<<1, 1024, 0, stream>>>(bsum, boff, nb);
    scan_write_kernel<<<nb, 256, 0, stream>>>(cnt, boff, row_ptr, cursor, dinv, N, E);
    fill_kernel<<<(E + 255) / 256, 256, 0, stream>>>(rowi, coli, dinv, cursor, csr, E);
    wcvt_kernel<<<64, 256, 0, stream>>>(W1, R1, W2, R2, Wt);
    wc_kernel<<<16, 256, 0, stream>>>(W3, Wh, Wt + 4 * 16384);

    int gb = (N + 63) / 64;
    int sb = (N + 3) / 4;
    _Float16* Wt1 = Wt;
    _Float16* Rt1 = Wt + 16384;
    _Float16* Wt2 = Wt + 2 * 16384;
    _Float16* Rt2 = Wt + 3 * 16384;
    _Float16* Wtc = Wt + 4 * 16384;

    // layer 1: H=B0h, XR=B1h (fp32 x converted in staging), x1 -> B1h
    gemm_dual_kernel<1><<<gb, 256, 0, stream>>>(x, Wt1, Rt1, B0h, B1h, N);
    spmm_kernel<1, 0><<<sb, 256, 0, stream>>>(B0h, B1h, row_ptr, csr, dinv,
                                              B1h, nullptr, nullptr, N);
    // layer 2: H=B0h, XR=B2h, x2 -> B2h
    gemm_dual_kernel<0><<<gb, 256, 0, stream>>>(B1h, Wt2, Rt2, B0h, B2h, N);
    spmm_kernel<1, 0><<<sb, 256, 0, stream>>>(B0h, B2h, row_ptr, csr, dinv,
                                              B2h, nullptr, nullptr, N);
    // layer 3 + head (linearity): G = x2@(W3@Wh); out = A@G + bh (fp32)
    gemm_h_kernel<<<gb, 256, 0, stream>>>(B2h, Wtc, B0h, N);
    spmm_kernel<0, 1><<<sb, 256, 0, stream>>>(B0h, nullptr, row_ptr, csr, dinv,
                                              nullptr, out, bh, N);
}

// Round 7
// 296.329 us; speedup vs baseline: 2.1416x; 1.0652x over previous
//
#include <hip/hip_runtime.h>
#include <hip/hip_bf16.h>

// GCN stack: N=50000 nodes, E=600000 edges, D=128.
//  1. zero cnt; histogram col -> cnt
//  2. hierarchical scan -> row_ptr/cursor (+dinv folded); fill CSR by dest
//     (csr entry 4B: low16=src, high16=f16 norm)
//  3. wcvt_wc: W1,R1,W2,R2 -> f16 transposed; Wc = W3@Wh -> f16 transposed
//  4. L1/L2: dual f16-MFMA GEMM + SpMM relu; L3+head: gemm_h(Wc) + SpMM
//     writing fp32+bias into d_out
//
// R1: single-block scan -> hierarchical (634->542)
// R2: fp32 VALU GEMM -> f16 MFMA; SpMM unroll x4 (542->422)
// R3: all activations f16 (422->340)
// R4: SpMM 16B/lane + dual-GEMM fusion (340->317)
// R5: head folded into Wc=W3@Wh (317->316): lesson - GEMMs are ~3-5us,
//     harness fills dominate profile; SpMM is the remaining pool.
// R6: SpMM 1 node per 16-lane sub (4 nodes/wave, 16 gathers in flight,
//     full-lane epilogue, no shfl reduce); csr 8B->4B; wcvt+wc merged.

#define SCAN_CHUNK 1024

typedef _Float16 half8 __attribute__((ext_vector_type(8)));
typedef _Float16 half4 __attribute__((ext_vector_type(4)));
typedef float floatx4 __attribute__((ext_vector_type(4)));

__global__ void zero_int_kernel(int* __restrict__ p, int n) {
    int i = blockIdx.x * blockDim.x + threadIdx.x;
    if (i < n) p[i] = 0;
}

__global__ void hist_kernel(const int* __restrict__ col, int* __restrict__ cnt, int E) {
    int i = blockIdx.x * blockDim.x + threadIdx.x;
    if (i < E) atomicAdd(&cnt[col[i]], 1);
}

__global__ __launch_bounds__(256) void scan_reduce_kernel(
        const int* __restrict__ cnt, int* __restrict__ bsum, int n) {
    __shared__ int s[256];
    int b = blockIdx.x, t = threadIdx.x;
    int base = b * SCAN_CHUNK + t * 4;
    int v = 0;
    if (base + 3 < n) {
        int4 q = *(const int4*)&cnt[base];
        v = q.x + q.y + q.z + q.w;
    } else {
        for (int i = 0; i < 4; ++i) if (base + i < n) v += cnt[base + i];
    }
    s[t] = v;
    __syncthreads();
    for (int off = 128; off > 0; off >>= 1) {
        if (t < off) s[t] += s[t + off];
        __syncthreads();
    }
    if (t == 0) bsum[b] = s[0];
}

__global__ __launch_bounds__(1024) void scan_bsum_kernel(
        const int* __restrict__ bsum, int* __restrict__ boff, int nb) {
    __shared__ int s[1024];
    int t = threadIdx.x;
    s[t] = (t < nb) ? bsum[t] : 0;
    __syncthreads();
    for (int off = 1; off < 1024; off <<= 1) {
        int add = (t >= off) ? s[t - off] : 0;
        __syncthreads();
        s[t] += add;
        __syncthreads();
    }
    if (t < nb) boff[t] = (t == 0) ? 0 : s[t - 1];
}

// scan chunk write + dinv = rsqrt(cnt+1) folded in
__global__ __launch_bounds__(256) void scan_write_kernel(
        const int* __restrict__ cnt, const int* __restrict__ boff,
        int* __restrict__ row_ptr, int* __restrict__ cursor,
        float* __restrict__ dinv, int n, int E) {
    __shared__ int s[256];
    int b = blockIdx.x, t = threadIdx.x;
    int base = b * SCAN_CHUNK + t * 4;
    int v[4];
    int sum = 0;
    for (int i = 0; i < 4; ++i) {
        v[i] = (base + i < n) ? cnt[base + i] : 0;
        sum += v[i];
    }
    s[t] = sum;
    __syncthreads();
    for (int off = 1; off < 256; off <<= 1) {
        int add = (t >= off) ? s[t - off] : 0;
        __syncthreads();
        s[t] += add;
        __syncthreads();
    }
    int prefix = boff[b] + ((t == 0) ? 0 : s[t - 1]);
    for (int i = 0; i < 4; ++i) {
        if (base + i < n) {
            row_ptr[base + i] = prefix;
            cursor[base + i] = prefix;
            dinv[base + i] = rsqrtf((float)(v[i] + 1));
            prefix += v[i];
        }
    }
    if (b == 0 && t == 0) row_ptr[n] = E;
}

// csr entry: low16 = src node id (N<65536), high16 = f16 norm
__global__ void fill_kernel(const int* __restrict__ row, const int* __restrict__ colv,
                            const float* __restrict__ dinv, int* __restrict__ cursor,
                            unsigned* __restrict__ csr, int E) {
    int i = blockIdx.x * blockDim.x + threadIdx.x;
    if (i < E) {
        int r = row[i], c = colv[i];
        int p = atomicAdd(&cursor[c], 1);
        _Float16 nrm = (_Float16)(dinv[r] * dinv[c]);
        unsigned hn = (unsigned)__builtin_bit_cast(unsigned short, nrm);
        csr[p] = (unsigned)r | (hn << 16);
    }
}

// blocks 0..63: W1,R1,W2,R2 fp32 [k][c] -> f16 Wt[c][k].
// blocks 64..79: Wc = W3@Wh (fp32 accum) -> f16 transposed at Wt+4*16384.
__global__ __launch_bounds__(256) void wcvt_wc_kernel(
        const float* __restrict__ W1, const float* __restrict__ R1,
        const float* __restrict__ W2, const float* __restrict__ R2,
        const float* __restrict__ W3, const float* __restrict__ Wh,
        _Float16* __restrict__ Wt) {
    int b = blockIdx.x;
    int t = threadIdx.x;
    if (b < 64) {
        __shared__ float tile[32][33];
        int mat = b >> 4, tl = b & 15;
        const float* W = (mat == 0) ? W1 : (mat == 1) ? R1 : (mat == 2) ? W2 : R2;
        _Float16* T = Wt + (size_t)mat * 16384;
        int tr = (tl >> 2) * 32, tc = (tl & 3) * 32;
        int i = t >> 3, j4 = t & 7;
        float4 v = *(const float4*)&W[(tr + i) * 128 + tc + j4 * 4];
        tile[i][j4 * 4 + 0] = v.x;
        tile[i][j4 * 4 + 1] = v.y;
        tile[i][j4 * 4 + 2] = v.z;
        tile[i][j4 * 4 + 3] = v.w;
        __syncthreads();
        half4 h;
        h.x = (_Float16)tile[j4 * 4 + 0][i];
        h.y = (_Float16)tile[j4 * 4 + 1][i];
        h.z = (_Float16)tile[j4 * 4 + 2][i];
        h.w = (_Float16)tile[j4 * 4 + 3][i];
        *(half4*)&T[(tc + i) * 128 + tr + j4 * 4] = h;
    } else {
        int bb = b - 64;
        _Float16* Wtc = Wt + (size_t)4 * 16384;
        int c = bb * 8 + (t >> 5);
        int k0 = (t & 31) * 4;
        float acc0 = 0.f, acc1 = 0.f, acc2 = 0.f, acc3 = 0.f;
        for (int j = 0; j < 128; ++j) {
            float wh = Wh[j * 128 + c];
            acc0 = fmaf(W3[(k0 + 0) * 128 + j], wh, acc0);
            acc1 = fmaf(W3[(k0 + 1) * 128 + j], wh, acc1);
            acc2 = fmaf(W3[(k0 + 2) * 128 + j], wh, acc2);
            acc3 = fmaf(W3[(k0 + 3) * 128 + j], wh, acc3);
        }
        half4 h;
        h.x = (_Float16)acc0; h.y = (_Float16)acc1;
        h.z = (_Float16)acc2; h.w = (_Float16)acc3;
        *(half4*)&Wtc[c * 128 + k0] = h;
    }
}

// Dual GEMM: outA = X@WA, outB = X@WB. A staged once (fp32->f16 if F32IN),
// A-fragments cached in regs across both B passes (LDS Bt reused).
// Fragment layouts (HW-verified, guide §3): A[m=lane&15][k=quad*8+j],
// B[k=quad*8+j][n=lane&15], C/D col=lane&15 row=quad*4+reg.
template <int F32IN>
__global__ __launch_bounds__(256) void gemm_dual_kernel(
        const void* __restrict__ Xv, const _Float16* __restrict__ WtA,
        const _Float16* __restrict__ WtB, _Float16* __restrict__ outA,
        _Float16* __restrict__ outB, int n) {
    __shared__ _Float16 Af[64 * 136];
    __shared__ _Float16 Bt[128 * 136];
    int t = threadIdx.x;
    int r0 = blockIdx.x * 64;

    if (F32IN) {
        const float* X = (const float*)Xv;
#pragma unroll
        for (int i = 0; i < 8; ++i) {
            int flat = i * 256 + t;
            int r = flat >> 5, c4 = flat & 31;
            float4 v = make_float4(0.f, 0.f, 0.f, 0.f);
            if (r0 + r < n) v = ((const float4*)X)[(size_t)(r0 + r) * 32 + c4];
            half4 h;
            h.x = (_Float16)v.x; h.y = (_Float16)v.y;
            h.z = (_Float16)v.z; h.w = (_Float16)v.w;
            *(half4*)&Af[r * 136 + c4 * 4] = h;
        }
    } else {
        const _Float16* X = (const _Float16*)Xv;
#pragma unroll
        for (int i = 0; i < 4; ++i) {
            int flat = i * 256 + t;
            int r = flat >> 4, k8 = flat & 15;
            half8 v = {0, 0, 0, 0, 0, 0, 0, 0};
            if (r0 + r < n) v = *(const half8*)&X[(size_t)(r0 + r) * 128 + k8 * 8];
            *(half8*)&Af[r * 136 + k8 * 8] = v;
        }
    }
#pragma unroll
    for (int i = 0; i < 8; ++i) {
        int flat = i * 256 + t;
        int c = flat >> 4, k8 = flat & 15;
        *(half8*)&Bt[c * 136 + k8 * 8] = *(const half8*)&WtA[c * 128 + k8 * 8];
    }
    __syncthreads();

    int lane = t & 63, w = t >> 6;
    int m = lane & 15, q = lane >> 4;
    int rowb = r0 + w * 16 + q * 4;

    half8 a[4];
#pragma unroll
    for (int s = 0; s < 4; ++s)
        a[s] = *(const half8*)&Af[(w * 16 + m) * 136 + s * 32 + q * 8];

    floatx4 acc[8];
#pragma unroll
    for (int nt = 0; nt < 8; ++nt) acc[nt] = (floatx4){0.f, 0.f, 0.f, 0.f};
#pragma unroll
    for (int s = 0; s < 4; ++s)
#pragma unroll
        for (int nt = 0; nt < 8; ++nt) {
            half8 b = *(const half8*)&Bt[(nt * 16 + m) * 136 + s * 32 + q * 8];
            acc[nt] = __builtin_amdgcn_mfma_f32_16x16x32_f16(a[s], b, acc[nt], 0, 0, 0);
        }
    __syncthreads();
    // restage Bt with WtB; epilogue-A global stores overlap the staging
#pragma unroll
    for (int i = 0; i < 8; ++i) {
        int flat = i * 256 + t;
        int c = flat >> 4, k8 = flat & 15;
        *(half8*)&Bt[c * 136 + k8 * 8] = *(const half8*)&WtB[c * 128 + k8 * 8];
    }
#pragma unroll
    for (int nt = 0; nt < 8; ++nt) {
        int col = nt * 16 + m;
#pragma unroll
        for (int r = 0; r < 4; ++r) {
            int gr = rowb + r;
            if (gr < n) outA[(size_t)gr * 128 + col] = (_Float16)acc[nt][r];
        }
    }
    __syncthreads();

#pragma unroll
    for (int nt = 0; nt < 8; ++nt) acc[nt] = (floatx4){0.f, 0.f, 0.f, 0.f};
#pragma unroll
    for (int s = 0; s < 4; ++s)
#pragma unroll
        for (int nt = 0; nt < 8; ++nt) {
            half8 b = *(const half8*)&Bt[(nt * 16 + m) * 136 + s * 32 + q * 8];
            acc[nt] = __builtin_amdgcn_mfma_f32_16x16x32_f16(a[s], b, acc[nt], 0, 0, 0);
        }
#pragma unroll
    for (int nt = 0; nt < 8; ++nt) {
        int col = nt * 16 + m;
#pragma unroll
        for (int r = 0; r < 4; ++r) {
            int gr = rowb + r;
            if (gr < n) outB[(size_t)gr * 128 + col] = (_Float16)acc[nt][r];
        }
    }
}

// Single GEMM, f16 in / f16 out.
__global__ __launch_bounds__(256) void gemm_h_kernel(
        const _Float16* __restrict__ X, const _Float16* __restrict__ Wt,
        _Float16* __restrict__ out, int n) {
    __shared__ _Float16 Af[64 * 136];
    __shared__ _Float16 Bt[128 * 136];
    int t = threadIdx.x;
    int r0 = blockIdx.x * 64;

#pragma unroll
    for (int i = 0; i < 4; ++i) {
        int flat = i * 256 + t;
        int r = flat >> 4, k8 = flat & 15;
        half8 v = {0, 0, 0, 0, 0, 0, 0, 0};
        if (r0 + r < n) v = *(const half8*)&X[(size_t)(r0 + r) * 128 + k8 * 8];
        *(half8*)&Af[r * 136 + k8 * 8] = v;
    }
#pragma unroll
    for (int i = 0; i < 8; ++i) {
        int flat = i * 256 + t;
        int c = flat >> 4, k8 = flat & 15;
        *(half8*)&Bt[c * 136 + k8 * 8] = *(const half8*)&Wt[c * 128 + k8 * 8];
    }
    __syncthreads();

    int lane = t & 63, w = t >> 6;
    int m = lane & 15, q = lane >> 4;

    floatx4 acc[8];
#pragma unroll
    for (int nt = 0; nt < 8; ++nt) acc[nt] = (floatx4){0.f, 0.f, 0.f, 0.f};

#pragma unroll
    for (int s = 0; s < 4; ++s) {
        half8 a = *(const half8*)&Af[(w * 16 + m) * 136 + s * 32 + q * 8];
#pragma unroll
        for (int nt = 0; nt < 8; ++nt) {
            half8 b = *(const half8*)&Bt[(nt * 16 + m) * 136 + s * 32 + q * 8];
            acc[nt] = __builtin_amdgcn_mfma_f32_16x16x32_f16(a, b, acc[nt], 0, 0, 0);
        }
    }

    int rowb = r0 + w * 16 + q * 4;
#pragma unroll
    for (int nt = 0; nt < 8; ++nt) {
        int col = nt * 16 + m;
#pragma unroll
        for (int r = 0; r < 4; ++r) {
            int gr = rowb + r;
            if (gr < n) out[(size_t)gr * 128 + col] = (_Float16)acc[nt][r];
        }
    }
}

// SpMM: one 16-lane sub-group per node (4 nodes/wave). Lane = 16B (half8)
// feature slice. Edge loop unrolled x4 with predicated tail (clamped index,
// nrm=0) -> up to 16 independent gathers in flight per wave, all lanes
// active in epilogue, no cross-lane reduction.
// FINAL: write fp32 + bias into d_out (head folded); else f16 (+xr residual).
template <int RELU, int FINAL>
__global__ void spmm_kernel(const _Float16* __restrict__ h, const _Float16* __restrict__ xr,
                            const int* __restrict__ row_ptr, const unsigned* __restrict__ csr,
                            const float* __restrict__ dinv, _Float16* __restrict__ outh,
                            float* __restrict__ outf, const float* __restrict__ bias,
                            int n) {
    int gid = blockIdx.x * blockDim.x + threadIdx.x;
    int node = gid >> 4;
    int fl = gid & 15;   // feature slice: 8 f16 at fl*8
    if (node >= n) return;
    const half8* hp8 = (const half8*)h;

    float acc[8];
#pragma unroll
    for (int j = 0; j < 8; ++j) acc[j] = 0.f;

    int e0 = row_ptr[node], e1 = row_ptr[node + 1];
    for (int e = e0; e < e1; e += 4) {
        int i1 = e + 1, i2 = e + 2, i3 = e + 3;
        int a1 = i1 < e1, a2 = i2 < e1, a3 = i3 < e1;
        unsigned d0 = csr[e];
        unsigned d1 = csr[a1 ? i1 : e];
        unsigned d2 = csr[a2 ? i2 : e];
        unsigned d3 = csr[a3 ? i3 : e];
        half8 v0 = hp8[(size_t)(d0 & 0xffffu) * 16 + fl];
        half8 v1 = hp8[(size_t)(d1 & 0xffffu) * 16 + fl];
        half8 v2 = hp8[(size_t)(d2 & 0xffffu) * 16 + fl];
        half8 v3 = hp8[(size_t)(d3 & 0xffffu) * 16 + fl];
        float n0 = (float)__builtin_bit_cast(_Float16, (unsigned short)(d0 >> 16));
        float n1 = a1 ? (float)__builtin_bit_cast(_Float16, (unsigned short)(d1 >> 16)) : 0.f;
        float n2 = a2 ? (float)__builtin_bit_cast(_Float16, (unsigned short)(d2 >> 16)) : 0.f;
        float n3 = a3 ? (float)__builtin_bit_cast(_Float16, (unsigned short)(d3 >> 16)) : 0.f;
#pragma unroll
        for (int j = 0; j < 8; ++j) {
            acc[j] = fmaf(n0, (float)v0[j], acc[j]);
            acc[j] = fmaf(n1, (float)v1[j], acc[j]);
            acc[j] = fmaf(n2, (float)v2[j], acc[j]);
            acc[j] = fmaf(n3, (float)v3[j], acc[j]);
        }
    }

    // self loop
    float di = dinv[node];
    float w = di * di;
    half8 hv = hp8[(size_t)node * 16 + fl];
#pragma unroll
    for (int j = 0; j < 8; ++j) acc[j] = fmaf(w, (float)hv[j], acc[j]);
    if (!FINAL && xr) {
        half8 r = ((const half8*)xr)[(size_t)node * 16 + fl];
#pragma unroll
        for (int j = 0; j < 8; ++j) acc[j] += (float)r[j];
    }
    if (RELU) {
#pragma unroll
        for (int j = 0; j < 8; ++j) acc[j] = fmaxf(acc[j], 0.f);
    }
    if (FINAL) {
        float4 b0 = *(const float4*)&bias[fl * 8];
        float4 b1 = *(const float4*)&bias[fl * 8 + 4];
        float4 o0 = make_float4(acc[0] + b0.x, acc[1] + b0.y,
                                acc[2] + b0.z, acc[3] + b0.w);
        float4 o1 = make_float4(acc[4] + b1.x, acc[5] + b1.y,
                                acc[6] + b1.z, acc[7] + b1.w);
        ((float4*)outf)[(size_t)node * 32 + fl * 2] = o0;
        ((float4*)outf)[(size_t)node * 32 + fl * 2 + 1] = o1;
    } else {
        half8 o;
#pragma unroll
        for (int j = 0; j < 8; ++j) o[j] = (_Float16)acc[j];
        ((half8*)outh)[(size_t)node * 16 + fl] = o;
    }
}

extern "C" void kernel_launch(void* const* d_in, const int* in_sizes, int n_in,
                              void* d_out, int out_size, void* d_ws, size_t ws_size,
                              hipStream_t stream) {
    const float* x  = (const float*)d_in[0];
    const int*   ei = (const int*)d_in[1];
    const float* W1 = (const float*)d_in[2];
    const float* R1 = (const float*)d_in[3];
    const float* W2 = (const float*)d_in[4];
    const float* R2 = (const float*)d_in[5];
    const float* W3 = (const float*)d_in[6];
    const float* Wh = (const float*)d_in[7];
    const float* bh = (const float*)d_in[8];
    float* out = (float*)d_out;

    int N = in_sizes[0] / 128;
    int E = in_sizes[1] / 2;

    char* p = (char*)d_ws;
    auto alloc = [&](size_t bytes) {
        char* r = p;
        p += (bytes + 255) & ~(size_t)255;
        return r;
    };
    int*      cnt     = (int*)alloc((size_t)N * 4);
    int*      row_ptr = (int*)alloc((size_t)(N + 1) * 4);
    int*      cursor  = (int*)alloc((size_t)N * 4);
    float*    dinv    = (float*)alloc((size_t)N * 4);
    int*      bsum    = (int*)alloc((size_t)1024 * 4);
    int*      boff    = (int*)alloc((size_t)1024 * 4);
    unsigned* csr     = (unsigned*)alloc((size_t)E * 4);
    _Float16* Wt      = (_Float16*)alloc((size_t)5 * 16384 * 2);
    _Float16* B0h     = (_Float16*)alloc((size_t)N * 128 * 2);
    _Float16* B1h     = (_Float16*)alloc((size_t)N * 128 * 2);
    _Float16* B2h     = (_Float16*)alloc((size_t)N * 128 * 2);

    const int* rowi = ei;
    const int* coli = ei + E;

    int nb = (N + SCAN_CHUNK - 1) / SCAN_CHUNK;

    zero_int_kernel<<<(N + 255) / 256, 256, 0, stream>>>(cnt, N);
    hist_kernel<<<(E + 255) / 256, 256, 0, stream>>>(coli, cnt, E);
    scan_reduce_kernel<<<nb, 256, 0, stream>>>(cnt, bsum, N);
    scan_bsum_kernel<<<1, 1024, 0, stream>>>(bsum, boff, nb);
    scan_write_kernel<<<nb, 256, 0, stream>>>(cnt, boff, row_ptr, cursor, dinv, N, E);
    fill_kernel<<<(E + 255) / 256, 256, 0, stream>>>(rowi, coli, dinv, cursor, csr, E);
    wcvt_wc_kernel<<<80, 256, 0, stream>>>(W1, R1, W2, R2, W3, Wh, Wt);

    int gb = (N + 63) / 64;
    int sb = ((size_t)N * 16 + 255) / 256;
    _Float16* Wt1 = Wt;
    _Float16* Rt1 = Wt + 16384;
    _Float16* Wt2 = Wt + 2 * 16384;
    _Float16* Rt2 = Wt + 3 * 16384;
    _Float16* Wtc = Wt + 4 * 16384;

    // layer 1: H=B0h, XR=B1h (fp32 x converted in staging), x1 -> B1h
    gemm_dual_kernel<1><<<gb, 256, 0, stream>>>(x, Wt1, Rt1, B0h, B1h, N);
    spmm_kernel<1, 0><<<sb, 256, 0, stream>>>(B0h, B1h, row_ptr, csr, dinv,
                                              B1h, nullptr, nullptr, N);
    // layer 2: H=B0h, XR=B2h, x2 -> B2h
    gemm_dual_kernel<0><<<gb, 256, 0, stream>>>(B1h, Wt2, Rt2, B0h, B2h, N);
    spmm_kernel<1, 0><<<sb, 256, 0, stream>>>(B0h, B2h, row_ptr, csr, dinv,
                                              B2h, nullptr, nullptr, N);
    // layer 3 + head (linearity): G = x2@(W3@Wh); out = A@G + bh (fp32)
    gemm_h_kernel<<<gb, 256, 0, stream>>>(B2h, Wtc, B0h, N);
    spmm_kernel<0, 1><<<sb, 256, 0, stream>>>(B0h, nullptr, row_ptr, csr, dinv,
                                              nullptr, out, bh, N);
}